// Round 2
// baseline (418.329 us; speedup 1.0000x reference)
//
#include <hip/hip_runtime.h>
#include <hip/hip_bf16.h>
#include <cstdint>
#include <cstddef>

// Problem constants
#define B_    2
#define S_    2048
#define HID_  2048
#define H_    32
#define HKV_  8
#define DH_   64
// SCALE * log2(e): scores scaled into exp2 domain
#define SC2_  0.1803368801111244f

typedef __bf16 bf16;
typedef bf16  bf16x2 __attribute__((ext_vector_type(2)));
typedef bf16  bf16x4 __attribute__((ext_vector_type(4)));
typedef bf16  bf16x8 __attribute__((ext_vector_type(8)));
typedef float f32x4  __attribute__((ext_vector_type(4)));
typedef float f32x16 __attribute__((ext_vector_type(16)));
typedef uint32_t u32x2 __attribute__((ext_vector_type(2)));

typedef __attribute__((address_space(3))) uint32_t  lds_u32_t;
typedef __attribute__((address_space(1))) const uint32_t glob_u32_t;

__device__ __forceinline__ void async16(const void* g, void* l) {
    __builtin_amdgcn_global_load_lds((glob_u32_t*)g, (lds_u32_t*)l, 16, 0, 0);
}

__device__ __forceinline__ bf16x8 cvt8(float4 a, float4 b) {
    bf16x8 r;
    r[0] = (bf16)a.x; r[1] = (bf16)a.y; r[2] = (bf16)a.z; r[3] = (bf16)a.w;
    r[4] = (bf16)b.x; r[5] = (bf16)b.y; r[6] = (bf16)b.z; r[7] = (bf16)b.w;
    return r;
}

__device__ __forceinline__ uint32_t pkbf(float a, float b) {
    bf16x2 t; t[0] = (bf16)a; t[1] = (bf16)b;
    return __builtin_bit_cast(uint32_t, t);
}
__device__ __forceinline__ bf16x8 mk8(uint32_t a, uint32_t b, uint32_t c, uint32_t d) {
    union { uint32_t u[4]; bf16x8 v; } t;
    t.u[0] = a; t.u[1] = b; t.u[2] = c; t.u[3] = d;
    return t.v;
}

// ---------------------------------------------------------------------------
// Merged fp32->bf16 convert for all 5 tensors (one launch).
// ---------------------------------------------------------------------------
__global__ __launch_bounds__(256) void cvt_all_kernel(
    const float* __restrict__ X,  const float* __restrict__ Wq,
    const float* __restrict__ Wk, const float* __restrict__ Wv,
    const float* __restrict__ Wo,
    bf16* __restrict__ Xb,  bf16* __restrict__ Wqb, bf16* __restrict__ Wkb,
    bf16* __restrict__ Wvb, bf16* __restrict__ Wob)
{
    const int i = blockIdx.x * 256 + threadIdx.x;
    const float* src; bf16* dst; int off;
    if (i < 1048576)      { src = X;  dst = Xb;  off = i; }
    else if (i < 1572864) { src = Wq; dst = Wqb; off = i - 1048576; }
    else if (i < 1703936) { src = Wk; dst = Wkb; off = i - 1572864; }
    else if (i < 1835008) { src = Wv; dst = Wvb; off = i - 1703936; }
    else                  { src = Wo; dst = Wob; off = i - 1835008; }
    float4 a = ((const float4*)src)[2 * off];
    float4 b = ((const float4*)src)[2 * off + 1];
    ((bf16x8*)dst)[off] = cvt8(a, b);
}

// ---------------------------------------------------------------------------
// Fused QKV projection GEMM (m97 structure). V written TRANSPOSED (b,hkv,d,s).
// Q is pre-scaled by SCALE*log2e so attn scores land in exp2 domain directly.
// ---------------------------------------------------------------------------
__global__ __launch_bounds__(256) void gemm_qkv_kernel(
    const bf16* __restrict__ A,
    const bf16* __restrict__ Wqb, const bf16* __restrict__ Wkb,
    const bf16* __restrict__ Wvb,
    const float* __restrict__ cs, const float* __restrict__ sn,
    bf16* __restrict__ Qo, bf16* __restrict__ Ko, bf16* __restrict__ Vt)
{
    __shared__ bf16 a_lds[128 * 64];
    __shared__ bf16 b_lds[128 * 64];

    const int tid  = threadIdx.x;
    const int wave = tid >> 6;
    const int lane = tid & 63;
    const int quad = lane >> 4;
    const int l16  = lane & 15;
    const int wm   = wave >> 1;
    const int wn   = wave & 1;
    const int m0   = blockIdx.x * 128;
    const int n0   = blockIdx.y * 128;

    f32x4 acc[4][4];
    #pragma unroll
    for (int mt = 0; mt < 4; ++mt)
        #pragma unroll
        for (int nt = 0; nt < 4; ++nt)
            acc[mt][nt] = (f32x4){0.f, 0.f, 0.f, 0.f};

    int srow[4], sgcol[4];
    const bf16* browp[4];
    #pragma unroll
    for (int i = 0; i < 4; ++i) {
        const int e = tid * 8 + i * 2048;
        srow[i] = e >> 6;
        const int chunk = (e >> 3) & 7;
        sgcol[i] = (chunk ^ (srow[i] & 7)) << 3;
        const int n = n0 + srow[i];
        browp[i] = (n < 2048) ? (Wqb + (size_t)n * HID_)
                 : (n < 2560) ? (Wkb + (size_t)(n - 2048) * HID_)
                              : (Wvb + (size_t)(n - 2560) * HID_);
    }

    for (int k0 = 0; k0 < HID_; k0 += 64) {
        #pragma unroll
        for (int i = 0; i < 4; ++i) {
            async16(A + (size_t)(m0 + srow[i]) * HID_ + k0 + sgcol[i],
                    &a_lds[tid * 8 + i * 2048]);
            async16(browp[i] + k0 + sgcol[i],
                    &b_lds[tid * 8 + i * 2048]);
        }
        __syncthreads();
        #pragma unroll
        for (int ks = 0; ks < 2; ++ks) {
            bf16x8 af[4], bfr[4];
            #pragma unroll
            for (int mt = 0; mt < 4; ++mt) {
                const int row = wm * 64 + mt * 16 + l16;
                const int c = (ks * 4 + quad) ^ (row & 7);
                af[mt] = *(const bf16x8*)(&a_lds[row * 64 + c * 8]);
            }
            #pragma unroll
            for (int nt = 0; nt < 4; ++nt) {
                const int row = wn * 64 + nt * 16 + l16;
                const int c = (ks * 4 + quad) ^ (row & 7);
                bfr[nt] = *(const bf16x8*)(&b_lds[row * 64 + c * 8]);
            }
            #pragma unroll
            for (int mt = 0; mt < 4; ++mt)
                #pragma unroll
                for (int nt = 0; nt < 4; ++nt)
                    acc[mt][nt] = __builtin_amdgcn_mfma_f32_16x16x32_bf16(
                        af[mt], bfr[nt], acc[mt][nt], 0, 0, 0);
        }
        __syncthreads();
    }

    const int nw = n0 + wn * 64;
    const int d  = l16;
    #pragma unroll
    for (int mt = 0; mt < 4; ++mt) {
        #pragma unroll
        for (int r = 0; r < 4; ++r) {
            const int m  = m0 + wm * 64 + mt * 16 + quad * 4 + r;
            const int bb = m >> 11;
            const int ss = m & (S_ - 1);
            const float v0 = acc[mt][0][r], v1 = acc[mt][1][r];
            const float v2 = acc[mt][2][r], v3 = acc[mt][3][r];
            if (nw < 2048) {
                const int h = nw >> 6;
                bf16* dp = Qo + ((size_t)(bb * H_ + h) * S_ + ss) * DH_;
                const float* cp = cs + ((size_t)bb * S_ + ss) * DH_;
                const float* sp = sn + ((size_t)bb * S_ + ss) * DH_;
                dp[ 0 + d] = (bf16)((v0 * cp[ 0 + d] - v2 * sp[ 0 + d]) * SC2_);
                dp[16 + d] = (bf16)((v1 * cp[16 + d] - v3 * sp[16 + d]) * SC2_);
                dp[32 + d] = (bf16)((v2 * cp[32 + d] + v0 * sp[32 + d]) * SC2_);
                dp[48 + d] = (bf16)((v3 * cp[48 + d] + v1 * sp[48 + d]) * SC2_);
            } else if (nw < 2560) {
                const int h = (nw - 2048) >> 6;
                bf16* dp = Ko + ((size_t)(bb * HKV_ + h) * S_ + ss) * DH_;
                const float* cp = cs + ((size_t)bb * S_ + ss) * DH_;
                const float* sp = sn + ((size_t)bb * S_ + ss) * DH_;
                dp[ 0 + d] = (bf16)(v0 * cp[ 0 + d] - v2 * sp[ 0 + d]);
                dp[16 + d] = (bf16)(v1 * cp[16 + d] - v3 * sp[16 + d]);
                dp[32 + d] = (bf16)(v2 * cp[32 + d] + v0 * sp[32 + d]);
                dp[48 + d] = (bf16)(v3 * cp[48 + d] + v1 * sp[48 + d]);
            } else {
                const int h = (nw - 2560) >> 6;
                bf16* dp = Vt + ((size_t)(bb * HKV_ + h) * DH_) * S_ + ss;
                dp[(size_t)( 0 + d) * S_] = (bf16)v0;
                dp[(size_t)(16 + d) * S_] = (bf16)v1;
                dp[(size_t)(32 + d) * S_] = (bf16)v2;
                dp[(size_t)(48 + d) * S_] = (bf16)v3;
            }
        }
    }
}

// ---------------------------------------------------------------------------
// Output projection: Y (4096 x 2048 fp32) = Ob (bf16, (b,s,h*d)) * Wob^T.
// ---------------------------------------------------------------------------
__global__ __launch_bounds__(256) void gemm_out_kernel(
    const bf16* __restrict__ A, const bf16* __restrict__ Wb,
    float* __restrict__ Y)
{
    __shared__ bf16 a_lds[128 * 64];
    __shared__ bf16 b_lds[128 * 64];

    const int tid  = threadIdx.x;
    const int wave = tid >> 6;
    const int lane = tid & 63;
    const int quad = lane >> 4;
    const int l16  = lane & 15;
    const int wm   = wave >> 1;
    const int wn   = wave & 1;
    const int m0   = blockIdx.x * 128;
    const int n0   = blockIdx.y * 128;

    f32x4 acc[4][4];
    #pragma unroll
    for (int mt = 0; mt < 4; ++mt)
        #pragma unroll
        for (int nt = 0; nt < 4; ++nt)
            acc[mt][nt] = (f32x4){0.f, 0.f, 0.f, 0.f};

    int srow[4], sgcol[4];
    #pragma unroll
    for (int i = 0; i < 4; ++i) {
        const int e = tid * 8 + i * 2048;
        srow[i] = e >> 6;
        const int chunk = (e >> 3) & 7;
        sgcol[i] = (chunk ^ (srow[i] & 7)) << 3;
    }

    for (int k0 = 0; k0 < HID_; k0 += 64) {
        #pragma unroll
        for (int i = 0; i < 4; ++i) {
            async16(A + (size_t)(m0 + srow[i]) * HID_ + k0 + sgcol[i],
                    &a_lds[tid * 8 + i * 2048]);
            async16(Wb + (size_t)(n0 + srow[i]) * HID_ + k0 + sgcol[i],
                    &b_lds[tid * 8 + i * 2048]);
        }
        __syncthreads();
        #pragma unroll
        for (int ks = 0; ks < 2; ++ks) {
            bf16x8 af[4], bfr[4];
            #pragma unroll
            for (int mt = 0; mt < 4; ++mt) {
                const int row = wm * 64 + mt * 16 + l16;
                const int c = (ks * 4 + quad) ^ (row & 7);
                af[mt] = *(const bf16x8*)(&a_lds[row * 64 + c * 8]);
            }
            #pragma unroll
            for (int nt = 0; nt < 4; ++nt) {
                const int row = wn * 64 + nt * 16 + l16;
                const int c = (ks * 4 + quad) ^ (row & 7);
                bfr[nt] = *(const bf16x8*)(&b_lds[row * 64 + c * 8]);
            }
            #pragma unroll
            for (int mt = 0; mt < 4; ++mt)
                #pragma unroll
                for (int nt = 0; nt < 4; ++nt)
                    acc[mt][nt] = __builtin_amdgcn_mfma_f32_16x16x32_bf16(
                        af[mt], bfr[nt], acc[mt][nt], 0, 0, 0);
        }
        __syncthreads();
    }

    #pragma unroll
    for (int mt = 0; mt < 4; ++mt)
        #pragma unroll
        for (int nt = 0; nt < 4; ++nt)
            #pragma unroll
            for (int r = 0; r < 4; ++r) {
                const int m = m0 + wm * 64 + mt * 16 + quad * 4 + r;
                const int n = n0 + wn * 64 + nt * 16 + l16;
                Y[(size_t)m * HID_ + n] = acc[mt][nt][r];
            }
}

// ---------------------------------------------------------------------------
// Flash attention v6 (causal, GQA), 32x32x16 MFMA.
// QK swapped (A=K, B=Q) -> S^T (col=q=lane&31); PV swapped (A=V^T, B=P^T) ->
// O^T (col=q) => all softmax state same-lane; stats need 1 shfl_xor(32).
// v6 vs v5: plain __launch_bounds__(256) — the (256,4) cap split the unified
// RF to 64 arch VGPRs and spilled ~125 MB to scratch (round-1 post-mortem).
// V-fragments now loaded after softmax/P-pack to shrink peak live range.
// Structure kept: merged k-loop (waves 0-1 -> tile p, waves 2-3 -> 31-p),
// grid.x=16 (1024 blocks, 4 blocks/CU at 128 VGPR), Q pre-scaled,
// permlane32_swap P-transpose, defer-max (THR=8).
// ---------------------------------------------------------------------------
__global__ __launch_bounds__(256) void attn_kernel(
    const bf16* __restrict__ Q, const bf16* __restrict__ K,
    const bf16* __restrict__ Vt, bf16* __restrict__ O)
{
    __shared__ bf16 k_lds[2][64 * 64];
    __shared__ bf16 v_lds[2][64 * 64];

    const int tid  = threadIdx.x;
    const int wave = tid >> 6;
    const int lane = tid & 63;
    const int l32  = lane & 31;
    const int half = lane >> 5;
    const int h  = blockIdx.y;
    const int b  = blockIdx.z;
    const int hkv = h >> 2;

    const bf16* Qg = Q  + (size_t)(b * H_ + h) * S_ * DH_;
    const bf16* Kg = K  + (size_t)(b * HKV_ + hkv) * S_ * DH_;
    const bf16* Vg = Vt + ((size_t)(b * HKV_ + hkv) * DH_) * S_;

    const int srow0  = tid >> 3;
    const int scolsw = ((tid & 7) ^ ((tid >> 3) & 7)) << 3;

    // q-sub-tile assignment: waves 0-1 -> tile p (small), waves 2-3 -> 31-p.
    const int p   = blockIdx.x;                 // 0..15
    const int st  = (wave < 2) ? p : (31 - p);
    const int qb0 = st * 64 + (wave & 1) * 32;
    const int qa  = qb0 + l32;
    const int nkt = 32 - p;                     // loop bound = larger tile's need

    // Q fragments, B-layout: n=l32 -> q, k = c*16 + half*8 + j -> dh
    bf16x8 qf[4];
    #pragma unroll
    for (int c = 0; c < 4; ++c)
        qf[c] = *(const bf16x8*)(Qg + (size_t)qa * DH_ + c * 16 + half * 8);

    f32x16 o_acc[2];
    #pragma unroll
    for (int dt = 0; dt < 2; ++dt)
        #pragma unroll
        for (int e = 0; e < 16; ++e) o_acc[dt][e] = 0.f;
    float m_i = -1e30f, l_i = 0.f;

    // prefetch tile 0
    #pragma unroll
    for (int i = 0; i < 2; ++i) {
        const int row = srow0 + i * 32;
        async16(Kg + (size_t)row * DH_ + scolsw, &k_lds[0][tid * 8 + i * 2048]);
        async16(Vg + (size_t)row * S_  + scolsw, &v_lds[0][tid * 8 + i * 2048]);
    }
    __syncthreads();

    for (int kt = 0; kt < nkt; ++kt) {
        if (kt + 1 < nkt) {
            bf16* kb = k_lds[(kt + 1) & 1];
            bf16* vb = v_lds[(kt + 1) & 1];
            #pragma unroll
            for (int i = 0; i < 2; ++i) {
                const int row = srow0 + i * 32;
                async16(Kg + (size_t)((kt + 1) * 64 + row) * DH_ + scolsw,
                        kb + tid * 8 + i * 2048);
                async16(Vg + (size_t)row * S_ + (kt + 1) * 64 + scolsw,
                        vb + tid * 8 + i * 2048);
            }
        }

        if (kt * 64 <= qb0 + 31) {
            const bf16* kb = k_lds[kt & 1];
            const bf16* vb = v_lds[kt & 1];
            const bool act1 = (kt * 64 + 32) <= (qb0 + 31);

            // scores tile 0 (kpos kt*64 .. +31); Q pre-scaled -> exp2 domain
            f32x16 s0, s1;
            {
                bf16x8 kf[4];
                #pragma unroll
                for (int c = 0; c < 4; ++c) {
                    const int row = l32;
                    const int col = ((2 * c + half) ^ (row & 7)) << 3;
                    kf[c] = *(const bf16x8*)(kb + row * 64 + col);
                }
                f32x16 a;
                #pragma unroll
                for (int e = 0; e < 16; ++e) a[e] = 0.f;
                #pragma unroll
                for (int c = 0; c < 4; ++c)
                    a = __builtin_amdgcn_mfma_f32_32x32x16_bf16(kf[c], qf[c], a, 0, 0, 0);
                s0 = a;
            }
            if (act1) {
                bf16x8 kf[4];
                #pragma unroll
                for (int c = 0; c < 4; ++c) {
                    const int row = 32 + l32;
                    const int col = ((2 * c + half) ^ (row & 7)) << 3;
                    kf[c] = *(const bf16x8*)(kb + row * 64 + col);
                }
                f32x16 a;
                #pragma unroll
                for (int e = 0; e < 16; ++e) a[e] = 0.f;
                #pragma unroll
                for (int c = 0; c < 4; ++c)
                    a = __builtin_amdgcn_mfma_f32_32x32x16_bf16(kf[c], qf[c], a, 0, 0, 0);
                s1 = a;
            }

            // causal mask (diagonal tiles only; full tiles need no pass)
            if (!((kt * 64 + 31) <= qb0)) {
                const int qrel = qa - kt * 64 - 4 * half;
                #pragma unroll
                for (int e = 0; e < 16; ++e)
                    if (((e & 3) + 8 * (e >> 2)) > qrel) s0[e] = -1e30f;
            }
            if (act1 && !((kt * 64 + 63) <= qb0)) {
                const int qrel = qa - kt * 64 - 32 - 4 * half;
                #pragma unroll
                for (int e = 0; e < 16; ++e)
                    if (((e & 3) + 8 * (e >> 2)) > qrel) s1[e] = -1e30f;
            }

            // stats (per-lane q, combine halves with one xor-32)
            float mx = s0[0];
            #pragma unroll
            for (int e = 1; e < 16; ++e) mx = fmaxf(mx, s0[e]);
            if (act1)
                #pragma unroll
                for (int e = 0; e < 16; ++e) mx = fmaxf(mx, s1[e]);
            mx = fmaxf(mx, __shfl_xor(mx, 32));

            // defer-max: only rescale when tile max grew past m_i + 8
            float al = 1.f;
            if (!__all(mx <= m_i + 8.f)) {
                const float mn = fmaxf(m_i, mx);
                al = exp2f(m_i - mn);
                m_i = mn;
                #pragma unroll
                for (int dt = 0; dt < 2; ++dt)
                    #pragma unroll
                    for (int e = 0; e < 16; ++e) o_acc[dt][e] *= al;
            }

            float sm = 0.f;
            #pragma unroll
            for (int e = 0; e < 16; ++e) {
                const float pp = exp2f(s0[e] - m_i);
                s0[e] = pp; sm += pp;
            }
            if (act1)
                #pragma unroll
                for (int e = 0; e < 16; ++e) {
                    const float pp = exp2f(s1[e] - m_i);
                    s1[e] = pp; sm += pp;
                }
            sm += __shfl_xor(sm, 32);
            l_i = l_i * al + sm;

            // P: C-layout -> B-layout via v_permlane32_swap.
            // {w0,w2} = swap(d0,d2): w0[l<32]=d0, w0[l>=32]=d2[l-32];
            //                        w2[l<32]=d0[l+32], w2[l>=32]=d2.
            bf16x8 pf[4];
            {
                uint32_t d0 = pkbf(s0[0],  s0[1]),  d1 = pkbf(s0[2],  s0[3]);
                uint32_t d2 = pkbf(s0[4],  s0[5]),  d3 = pkbf(s0[6],  s0[7]);
                uint32_t d4 = pkbf(s0[8],  s0[9]),  d5 = pkbf(s0[10], s0[11]);
                uint32_t d6 = pkbf(s0[12], s0[13]), d7 = pkbf(s0[14], s0[15]);
                u32x2 r02 = __builtin_amdgcn_permlane32_swap(d0, d2, false, false);
                u32x2 r13 = __builtin_amdgcn_permlane32_swap(d1, d3, false, false);
                u32x2 r46 = __builtin_amdgcn_permlane32_swap(d4, d6, false, false);
                u32x2 r57 = __builtin_amdgcn_permlane32_swap(d5, d7, false, false);
                pf[0] = mk8(r02[0], r13[0], r02[1], r13[1]);
                pf[1] = mk8(r46[0], r57[0], r46[1], r57[1]);
            }
            if (act1) {
                uint32_t d0 = pkbf(s1[0],  s1[1]),  d1 = pkbf(s1[2],  s1[3]);
                uint32_t d2 = pkbf(s1[4],  s1[5]),  d3 = pkbf(s1[6],  s1[7]);
                uint32_t d4 = pkbf(s1[8],  s1[9]),  d5 = pkbf(s1[10], s1[11]);
                uint32_t d6 = pkbf(s1[12], s1[13]), d7 = pkbf(s1[14], s1[15]);
                u32x2 r02 = __builtin_amdgcn_permlane32_swap(d0, d2, false, false);
                u32x2 r13 = __builtin_amdgcn_permlane32_swap(d1, d3, false, false);
                u32x2 r46 = __builtin_amdgcn_permlane32_swap(d4, d6, false, false);
                u32x2 r57 = __builtin_amdgcn_permlane32_swap(d5, d7, false, false);
                pf[2] = mk8(r02[0], r13[0], r02[1], r13[1]);
                pf[3] = mk8(r46[0], r57[0], r46[1], r57[1]);
            }

            // V^T A-frags (loaded late, only needed for PV):
            // vf[dt][c] = V^T[dt*32+l32][c*16+half*8 ..+8]
            bf16x8 vf[2][4];
            #pragma unroll
            for (int dt = 0; dt < 2; ++dt)
                #pragma unroll
                for (int c = 0; c < 4; ++c) {
                    const int row = dt * 32 + l32;
                    const int col = ((2 * c + half) ^ (row & 7)) << 3;
                    vf[dt][c] = *(const bf16x8*)(vb + row * 64 + col);
                }

            // O^T += V^T * P^T over kpos chunks
            const int nc = act1 ? 4 : 2;
            #pragma unroll
            for (int c = 0; c < 4; ++c) {
                if (c >= nc) break;
                #pragma unroll
                for (int dt = 0; dt < 2; ++dt)
                    o_acc[dt] = __builtin_amdgcn_mfma_f32_32x32x16_bf16(
                        vf[dt][c], pf[c], o_acc[dt], 0, 0, 0);
            }
        }
        __syncthreads();
    }

    // epilogue: O^T C-layout -> Ob (b, s, h*64+d); q = l32 same-lane
    const float inv = 1.f / l_i;
    bf16* op = O + ((size_t)(b * S_ + qa) * H_ + h) * DH_;
    #pragma unroll
    for (int dt = 0; dt < 2; ++dt)
        #pragma unroll
        for (int g = 0; g < 4; ++g) {
            bf16x4 ov;
            #pragma unroll
            for (int r = 0; r < 4; ++r) ov[r] = (bf16)(o_acc[dt][g * 4 + r] * inv);
            *(bf16x4*)(op + dt * 32 + g * 8 + half * 4) = ov;
        }
}

// ---------------------------------------------------------------------------
extern "C" void kernel_launch(void* const* d_in, const int* in_sizes, int n_in,
                              void* d_out, int out_size, void* d_ws, size_t ws_size,
                              hipStream_t stream)
{
    const float* X    = (const float*)d_in[0];
    const float* cs   = (const float*)d_in[1];
    const float* sn   = (const float*)d_in[2];
    const float* Wq   = (const float*)d_in[4];
    const float* Wk   = (const float*)d_in[5];
    const float* Wv   = (const float*)d_in[6];
    const float* Wo   = (const float*)d_in[7];
    float* Y          = (float*)d_out;

    bf16* Xb  = (bf16*)d_ws;                       // 8388608
    bf16* Wqb = Xb  + (size_t)8388608;             // 4194304
    bf16* Wkb = Wqb + (size_t)4194304;             // 1048576
    bf16* Wvb = Wkb + (size_t)1048576;             // 1048576
    bf16* Wob = Wvb + (size_t)1048576;             // 4194304
    bf16* Qb  = Wob + (size_t)4194304;             // 8388608
    bf16* Kb  = Qb  + (size_t)8388608;             // 2097152
    bf16* Vtb = Kb  + (size_t)2097152;             // 2097152 (transposed d,s)
    bf16* Ob  = Vtb + (size_t)2097152;             // 8388608

    dim3 blk(256);
    cvt_all_kernel<<<dim3(9216), blk, 0, stream>>>(X, Wq, Wk, Wv, Wo,
                                                   Xb, Wqb, Wkb, Wvb, Wob);
    gemm_qkv_kernel<<<dim3(32, 24), blk, 0, stream>>>(Xb, Wqb, Wkb, Wvb,
                                                      cs, sn, Qb, Kb, Vtb);
    attn_kernel<<<dim3(16, H_, B_), blk, 0, stream>>>(Qb, Kb, Vtb, Ob);
    gemm_out_kernel<<<dim3(32, 16), blk, 0, stream>>>(Ob, Wob, Y);
}

// Round 3
// 391.610 us; speedup vs baseline: 1.0682x; 1.0682x over previous
//
#include <hip/hip_runtime.h>
#include <hip/hip_bf16.h>
#include <cstdint>
#include <cstddef>

// Problem constants
#define B_    2
#define S_    2048
#define HID_  2048
#define H_    32
#define HKV_  8
#define DH_   64
// SCALE * log2(e): scores scaled into exp2 domain
#define SC2_  0.1803368801111244f

typedef __bf16 bf16;
typedef bf16  bf16x2 __attribute__((ext_vector_type(2)));
typedef bf16  bf16x4 __attribute__((ext_vector_type(4)));
typedef bf16  bf16x8 __attribute__((ext_vector_type(8)));
typedef float f32x4  __attribute__((ext_vector_type(4)));
typedef float f32x16 __attribute__((ext_vector_type(16)));
typedef uint32_t u32x2 __attribute__((ext_vector_type(2)));

typedef __attribute__((address_space(3))) uint32_t  lds_u32_t;
typedef __attribute__((address_space(1))) const uint32_t glob_u32_t;

__device__ __forceinline__ void async16(const void* g, void* l) {
    __builtin_amdgcn_global_load_lds((glob_u32_t*)g, (lds_u32_t*)l, 16, 0, 0);
}

__device__ __forceinline__ bf16x8 cvt8(float4 a, float4 b) {
    bf16x8 r;
    r[0] = (bf16)a.x; r[1] = (bf16)a.y; r[2] = (bf16)a.z; r[3] = (bf16)a.w;
    r[4] = (bf16)b.x; r[5] = (bf16)b.y; r[6] = (bf16)b.z; r[7] = (bf16)b.w;
    return r;
}

__device__ __forceinline__ uint32_t pkbf(float a, float b) {
    bf16x2 t; t[0] = (bf16)a; t[1] = (bf16)b;
    return __builtin_bit_cast(uint32_t, t);
}
__device__ __forceinline__ bf16x8 mk8(uint32_t a, uint32_t b, uint32_t c, uint32_t d) {
    union { uint32_t u[4]; bf16x8 v; } t;
    t.u[0] = a; t.u[1] = b; t.u[2] = c; t.u[3] = d;
    return t.v;
}

// ---------------------------------------------------------------------------
// Merged fp32->bf16 convert for all 5 tensors (one launch).
// ---------------------------------------------------------------------------
__global__ __launch_bounds__(256) void cvt_all_kernel(
    const float* __restrict__ X,  const float* __restrict__ Wq,
    const float* __restrict__ Wk, const float* __restrict__ Wv,
    const float* __restrict__ Wo,
    bf16* __restrict__ Xb,  bf16* __restrict__ Wqb, bf16* __restrict__ Wkb,
    bf16* __restrict__ Wvb, bf16* __restrict__ Wob)
{
    const int i = blockIdx.x * 256 + threadIdx.x;
    const float* src; bf16* dst; int off;
    if (i < 1048576)      { src = X;  dst = Xb;  off = i; }
    else if (i < 1572864) { src = Wq; dst = Wqb; off = i - 1048576; }
    else if (i < 1703936) { src = Wk; dst = Wkb; off = i - 1572864; }
    else if (i < 1835008) { src = Wv; dst = Wvb; off = i - 1703936; }
    else                  { src = Wo; dst = Wob; off = i - 1835008; }
    float4 a = ((const float4*)src)[2 * off];
    float4 b = ((const float4*)src)[2 * off + 1];
    ((bf16x8*)dst)[off] = cvt8(a, b);
}

// ---------------------------------------------------------------------------
// Fused QKV projection GEMM (m97 structure). V written TRANSPOSED (b,hkv,d,s).
// Q is pre-scaled by SCALE*log2e so attn scores land in exp2 domain directly.
// ---------------------------------------------------------------------------
__global__ __launch_bounds__(256) void gemm_qkv_kernel(
    const bf16* __restrict__ A,
    const bf16* __restrict__ Wqb, const bf16* __restrict__ Wkb,
    const bf16* __restrict__ Wvb,
    const float* __restrict__ cs, const float* __restrict__ sn,
    bf16* __restrict__ Qo, bf16* __restrict__ Ko, bf16* __restrict__ Vt)
{
    __shared__ bf16 a_lds[128 * 64];
    __shared__ bf16 b_lds[128 * 64];

    const int tid  = threadIdx.x;
    const int wave = tid >> 6;
    const int lane = tid & 63;
    const int quad = lane >> 4;
    const int l16  = lane & 15;
    const int wm   = wave >> 1;
    const int wn   = wave & 1;
    const int m0   = blockIdx.x * 128;
    const int n0   = blockIdx.y * 128;

    f32x4 acc[4][4];
    #pragma unroll
    for (int mt = 0; mt < 4; ++mt)
        #pragma unroll
        for (int nt = 0; nt < 4; ++nt)
            acc[mt][nt] = (f32x4){0.f, 0.f, 0.f, 0.f};

    int srow[4], sgcol[4];
    const bf16* browp[4];
    #pragma unroll
    for (int i = 0; i < 4; ++i) {
        const int e = tid * 8 + i * 2048;
        srow[i] = e >> 6;
        const int chunk = (e >> 3) & 7;
        sgcol[i] = (chunk ^ (srow[i] & 7)) << 3;
        const int n = n0 + srow[i];
        browp[i] = (n < 2048) ? (Wqb + (size_t)n * HID_)
                 : (n < 2560) ? (Wkb + (size_t)(n - 2048) * HID_)
                              : (Wvb + (size_t)(n - 2560) * HID_);
    }

    for (int k0 = 0; k0 < HID_; k0 += 64) {
        #pragma unroll
        for (int i = 0; i < 4; ++i) {
            async16(A + (size_t)(m0 + srow[i]) * HID_ + k0 + sgcol[i],
                    &a_lds[tid * 8 + i * 2048]);
            async16(browp[i] + k0 + sgcol[i],
                    &b_lds[tid * 8 + i * 2048]);
        }
        __syncthreads();
        #pragma unroll
        for (int ks = 0; ks < 2; ++ks) {
            bf16x8 af[4], bfr[4];
            #pragma unroll
            for (int mt = 0; mt < 4; ++mt) {
                const int row = wm * 64 + mt * 16 + l16;
                const int c = (ks * 4 + quad) ^ (row & 7);
                af[mt] = *(const bf16x8*)(&a_lds[row * 64 + c * 8]);
            }
            #pragma unroll
            for (int nt = 0; nt < 4; ++nt) {
                const int row = wn * 64 + nt * 16 + l16;
                const int c = (ks * 4 + quad) ^ (row & 7);
                bfr[nt] = *(const bf16x8*)(&b_lds[row * 64 + c * 8]);
            }
            #pragma unroll
            for (int mt = 0; mt < 4; ++mt)
                #pragma unroll
                for (int nt = 0; nt < 4; ++nt)
                    acc[mt][nt] = __builtin_amdgcn_mfma_f32_16x16x32_bf16(
                        af[mt], bfr[nt], acc[mt][nt], 0, 0, 0);
        }
        __syncthreads();
    }

    const int nw = n0 + wn * 64;
    const int d  = l16;
    #pragma unroll
    for (int mt = 0; mt < 4; ++mt) {
        #pragma unroll
        for (int r = 0; r < 4; ++r) {
            const int m  = m0 + wm * 64 + mt * 16 + quad * 4 + r;
            const int bb = m >> 11;
            const int ss = m & (S_ - 1);
            const float v0 = acc[mt][0][r], v1 = acc[mt][1][r];
            const float v2 = acc[mt][2][r], v3 = acc[mt][3][r];
            if (nw < 2048) {
                const int h = nw >> 6;
                bf16* dp = Qo + ((size_t)(bb * H_ + h) * S_ + ss) * DH_;
                const float* cp = cs + ((size_t)bb * S_ + ss) * DH_;
                const float* sp = sn + ((size_t)bb * S_ + ss) * DH_;
                dp[ 0 + d] = (bf16)((v0 * cp[ 0 + d] - v2 * sp[ 0 + d]) * SC2_);
                dp[16 + d] = (bf16)((v1 * cp[16 + d] - v3 * sp[16 + d]) * SC2_);
                dp[32 + d] = (bf16)((v2 * cp[32 + d] + v0 * sp[32 + d]) * SC2_);
                dp[48 + d] = (bf16)((v3 * cp[48 + d] + v1 * sp[48 + d]) * SC2_);
            } else if (nw < 2560) {
                const int h = (nw - 2048) >> 6;
                bf16* dp = Ko + ((size_t)(bb * HKV_ + h) * S_ + ss) * DH_;
                const float* cp = cs + ((size_t)bb * S_ + ss) * DH_;
                const float* sp = sn + ((size_t)bb * S_ + ss) * DH_;
                dp[ 0 + d] = (bf16)(v0 * cp[ 0 + d] - v2 * sp[ 0 + d]);
                dp[16 + d] = (bf16)(v1 * cp[16 + d] - v3 * sp[16 + d]);
                dp[32 + d] = (bf16)(v2 * cp[32 + d] + v0 * sp[32 + d]);
                dp[48 + d] = (bf16)(v3 * cp[48 + d] + v1 * sp[48 + d]);
            } else {
                const int h = (nw - 2560) >> 6;
                bf16* dp = Vt + ((size_t)(bb * HKV_ + h) * DH_) * S_ + ss;
                dp[(size_t)( 0 + d) * S_] = (bf16)v0;
                dp[(size_t)(16 + d) * S_] = (bf16)v1;
                dp[(size_t)(32 + d) * S_] = (bf16)v2;
                dp[(size_t)(48 + d) * S_] = (bf16)v3;
            }
        }
    }
}

// ---------------------------------------------------------------------------
// Output projection: Y (4096 x 2048 fp32) = Ob (bf16, (b,s,h*d)) * Wob^T.
// ---------------------------------------------------------------------------
__global__ __launch_bounds__(256) void gemm_out_kernel(
    const bf16* __restrict__ A, const bf16* __restrict__ Wb,
    float* __restrict__ Y)
{
    __shared__ bf16 a_lds[128 * 64];
    __shared__ bf16 b_lds[128 * 64];

    const int tid  = threadIdx.x;
    const int wave = tid >> 6;
    const int lane = tid & 63;
    const int quad = lane >> 4;
    const int l16  = lane & 15;
    const int wm   = wave >> 1;
    const int wn   = wave & 1;
    const int m0   = blockIdx.x * 128;
    const int n0   = blockIdx.y * 128;

    f32x4 acc[4][4];
    #pragma unroll
    for (int mt = 0; mt < 4; ++mt)
        #pragma unroll
        for (int nt = 0; nt < 4; ++nt)
            acc[mt][nt] = (f32x4){0.f, 0.f, 0.f, 0.f};

    int srow[4], sgcol[4];
    #pragma unroll
    for (int i = 0; i < 4; ++i) {
        const int e = tid * 8 + i * 2048;
        srow[i] = e >> 6;
        const int chunk = (e >> 3) & 7;
        sgcol[i] = (chunk ^ (srow[i] & 7)) << 3;
    }

    for (int k0 = 0; k0 < HID_; k0 += 64) {
        #pragma unroll
        for (int i = 0; i < 4; ++i) {
            async16(A + (size_t)(m0 + srow[i]) * HID_ + k0 + sgcol[i],
                    &a_lds[tid * 8 + i * 2048]);
            async16(Wb + (size_t)(n0 + srow[i]) * HID_ + k0 + sgcol[i],
                    &b_lds[tid * 8 + i * 2048]);
        }
        __syncthreads();
        #pragma unroll
        for (int ks = 0; ks < 2; ++ks) {
            bf16x8 af[4], bfr[4];
            #pragma unroll
            for (int mt = 0; mt < 4; ++mt) {
                const int row = wm * 64 + mt * 16 + l16;
                const int c = (ks * 4 + quad) ^ (row & 7);
                af[mt] = *(const bf16x8*)(&a_lds[row * 64 + c * 8]);
            }
            #pragma unroll
            for (int nt = 0; nt < 4; ++nt) {
                const int row = wn * 64 + nt * 16 + l16;
                const int c = (ks * 4 + quad) ^ (row & 7);
                bfr[nt] = *(const bf16x8*)(&b_lds[row * 64 + c * 8]);
            }
            #pragma unroll
            for (int mt = 0; mt < 4; ++mt)
                #pragma unroll
                for (int nt = 0; nt < 4; ++nt)
                    acc[mt][nt] = __builtin_amdgcn_mfma_f32_16x16x32_bf16(
                        af[mt], bfr[nt], acc[mt][nt], 0, 0, 0);
        }
        __syncthreads();
    }

    #pragma unroll
    for (int mt = 0; mt < 4; ++mt)
        #pragma unroll
        for (int nt = 0; nt < 4; ++nt)
            #pragma unroll
            for (int r = 0; r < 4; ++r) {
                const int m = m0 + wm * 64 + mt * 16 + quad * 4 + r;
                const int n = n0 + wn * 64 + nt * 16 + l16;
                Y[(size_t)m * HID_ + n] = acc[mt][nt][r];
            }
}

// ---------------------------------------------------------------------------
// Flash attention v7 (causal, GQA), 32x32x16 MFMA.
// QK swapped (A=K, B=Q) -> S^T (col=q=lane&31); PV swapped (A=V^T, B=P^T) ->
// O^T (col=q) => all softmax state same-lane; stats need 1 shfl_xor(32).
// v7 vs v6 (round-2 post-mortem): the merged pair wasted ~33% of wave-slots
// (waves 0-1 spun at barriers past iteration p). De-paired: ONE 128-row
// q-tile per block, all 4 waves active every iteration (>=96% packed),
// nkt = 4*qt+4. KVBLK 64 -> 32: single score tile per iter (no s1/act1
// path, lower live VGPR), K/V tiles 4 KB each double-buffered -> LDS 16 KB
// (was 32) so whichever of {LDS, unified VGPR+AGPR} caps residency, more
// blocks fit. 1024 blocks; dispatch swizzle spreads qt so co-resident
// blocks on a CU have mixed work sizes. Kept: Q pre-scaled, permlane32_swap
// P-transpose, defer-max (THR=8), plain __launch_bounds__(256).
// ---------------------------------------------------------------------------
__global__ __launch_bounds__(256) void attn_kernel(
    const bf16* __restrict__ Q, const bf16* __restrict__ K,
    const bf16* __restrict__ Vt, bf16* __restrict__ O)
{
    __shared__ bf16 k_lds[2][32 * 64];
    __shared__ bf16 v_lds[2][32 * 64];

    const int tid  = threadIdx.x;
    const int wave = tid >> 6;
    const int lane = tid & 63;
    const int l32  = lane & 31;
    const int half = lane >> 5;
    const int h  = blockIdx.y;
    const int b  = blockIdx.z;
    const int hkv = h >> 2;

    const bf16* Qg = Q  + (size_t)(b * H_ + h) * S_ * DH_;
    const bf16* Kg = K  + (size_t)(b * HKV_ + hkv) * S_ * DH_;
    const bf16* Vg = Vt + ((size_t)(b * HKV_ + hkv) * DH_) * S_;

    // balance swizzle: co-scheduled blocks (same blockIdx.x) get mixed qt
    const int qt  = 15 - ((blockIdx.x + 4 * ((h >> 4) + 2 * b)) & 15);
    const int qb0 = qt * 128 + wave * 32;
    const int qa  = qb0 + l32;
    const int nkt = 4 * qt + 4;

    // staging indices (pre-swizzled global source, linear LDS dest).
    // K tile: 32 kpos rows x 64 dh.  V^T tile stored as [32][8 chunks]:
    // element (d, scol8) at row d&31, chunk ((d>>5)*4 + scol8) ^ (d&7).
    const int kr = tid >> 3;                    // 0..31
    const int kj = ((tid & 7) ^ (kr & 7)) << 3; // dh col for K source
    const int vj = (tid & 7) ^ (kr & 7);        // unswizzled V chunk
    const int vd = kr + 32 * (vj >> 2);         // V^T d row
    const int vs = (vj & 3) * 8;                // V^T s col offset

    // Q fragments, B-layout: n=l32 -> q, k = c*16 + half*8 + j -> dh
    bf16x8 qf[4];
    #pragma unroll
    for (int c = 0; c < 4; ++c)
        qf[c] = *(const bf16x8*)(Qg + (size_t)qa * DH_ + c * 16 + half * 8);

    f32x16 o_acc[2];
    #pragma unroll
    for (int dt = 0; dt < 2; ++dt)
        #pragma unroll
        for (int e = 0; e < 16; ++e) o_acc[dt][e] = 0.f;
    float m_i = -1e30f, l_i = 0.f;

    // prefetch tile 0
    async16(Kg + (size_t)kr * DH_ + kj,  &k_lds[0][tid * 8]);
    async16(Vg + (size_t)vd * S_  + vs,  &v_lds[0][tid * 8]);
    __syncthreads();

    for (int kt = 0; kt < nkt; ++kt) {
        if (kt + 1 < nkt) {
            async16(Kg + (size_t)((kt + 1) * 32 + kr) * DH_ + kj,
                    &k_lds[(kt + 1) & 1][tid * 8]);
            async16(Vg + (size_t)vd * S_ + (kt + 1) * 32 + vs,
                    &v_lds[(kt + 1) & 1][tid * 8]);
        }

        if (kt * 32 <= qb0 + 31) {
            const bf16* kb = k_lds[kt & 1];
            const bf16* vb = v_lds[kt & 1];

            // scores (32 kpos x 32 q); Q pre-scaled -> exp2 domain
            f32x16 s0;
            {
                bf16x8 kf[4];
                #pragma unroll
                for (int c = 0; c < 4; ++c) {
                    const int ch = (2 * c + half) ^ (l32 & 7);
                    kf[c] = *(const bf16x8*)(kb + l32 * 64 + ch * 8);
                }
                f32x16 a;
                #pragma unroll
                for (int e = 0; e < 16; ++e) a[e] = 0.f;
                #pragma unroll
                for (int c = 0; c < 4; ++c)
                    a = __builtin_amdgcn_mfma_f32_32x32x16_bf16(kf[c], qf[c], a, 0, 0, 0);
                s0 = a;
            }

            // causal mask (exactly one partial tile per wave: kt*32 == qb0)
            if (!((kt * 32 + 31) <= qb0)) {
                const int qrel = qa - kt * 32 - 4 * half;
                #pragma unroll
                for (int e = 0; e < 16; ++e)
                    if (((e & 3) + 8 * (e >> 2)) > qrel) s0[e] = -1e30f;
            }

            // stats (per-lane q, combine halves with one xor-32)
            float mx = s0[0];
            #pragma unroll
            for (int e = 1; e < 16; ++e) mx = fmaxf(mx, s0[e]);
            mx = fmaxf(mx, __shfl_xor(mx, 32));

            // defer-max: only rescale when tile max grew past m_i + 8
            float al = 1.f;
            if (!__all(mx <= m_i + 8.f)) {
                const float mn = fmaxf(m_i, mx);
                al = exp2f(m_i - mn);
                m_i = mn;
                #pragma unroll
                for (int dt = 0; dt < 2; ++dt)
                    #pragma unroll
                    for (int e = 0; e < 16; ++e) o_acc[dt][e] *= al;
            }

            float sm = 0.f;
            #pragma unroll
            for (int e = 0; e < 16; ++e) {
                const float pp = exp2f(s0[e] - m_i);
                s0[e] = pp; sm += pp;
            }
            sm += __shfl_xor(sm, 32);
            l_i = l_i * al + sm;

            // P: C-layout -> B-layout via v_permlane32_swap
            bf16x8 pf[2];
            {
                uint32_t d0 = pkbf(s0[0],  s0[1]),  d1 = pkbf(s0[2],  s0[3]);
                uint32_t d2 = pkbf(s0[4],  s0[5]),  d3 = pkbf(s0[6],  s0[7]);
                uint32_t d4 = pkbf(s0[8],  s0[9]),  d5 = pkbf(s0[10], s0[11]);
                uint32_t d6 = pkbf(s0[12], s0[13]), d7 = pkbf(s0[14], s0[15]);
                u32x2 r02 = __builtin_amdgcn_permlane32_swap(d0, d2, false, false);
                u32x2 r13 = __builtin_amdgcn_permlane32_swap(d1, d3, false, false);
                u32x2 r46 = __builtin_amdgcn_permlane32_swap(d4, d6, false, false);
                u32x2 r57 = __builtin_amdgcn_permlane32_swap(d5, d7, false, false);
                pf[0] = mk8(r02[0], r13[0], r02[1], r13[1]);
                pf[1] = mk8(r46[0], r57[0], r46[1], r57[1]);
            }

            // V^T A-frags (loaded late, only needed for PV):
            // vf[dt][c] = V^T[dt*32+l32][kpos chunk c*16+half*8 ..+8]
            bf16x8 vf[2][2];
            #pragma unroll
            for (int dt = 0; dt < 2; ++dt)
                #pragma unroll
                for (int c = 0; c < 2; ++c) {
                    const int ch = (dt * 4 + 2 * c + half) ^ (l32 & 7);
                    vf[dt][c] = *(const bf16x8*)(vb + l32 * 64 + ch * 8);
                }

            // O^T += V^T * P^T
            #pragma unroll
            for (int c = 0; c < 2; ++c)
                #pragma unroll
                for (int dt = 0; dt < 2; ++dt)
                    o_acc[dt] = __builtin_amdgcn_mfma_f32_32x32x16_bf16(
                        vf[dt][c], pf[c], o_acc[dt], 0, 0, 0);
        }
        __syncthreads();
    }

    // epilogue: O^T C-layout -> Ob (b, s, h*64+d); q = l32 same-lane
    const float inv = 1.f / l_i;
    bf16* op = O + ((size_t)(b * S_ + qa) * H_ + h) * DH_;
    #pragma unroll
    for (int dt = 0; dt < 2; ++dt)
        #pragma unroll
        for (int g = 0; g < 4; ++g) {
            bf16x4 ov;
            #pragma unroll
            for (int r = 0; r < 4; ++r) ov[r] = (bf16)(o_acc[dt][g * 4 + r] * inv);
            *(bf16x4*)(op + dt * 32 + g * 8 + half * 4) = ov;
        }
}

// ---------------------------------------------------------------------------
extern "C" void kernel_launch(void* const* d_in, const int* in_sizes, int n_in,
                              void* d_out, int out_size, void* d_ws, size_t ws_size,
                              hipStream_t stream)
{
    const float* X    = (const float*)d_in[0];
    const float* cs   = (const float*)d_in[1];
    const float* sn   = (const float*)d_in[2];
    const float* Wq   = (const float*)d_in[4];
    const float* Wk   = (const float*)d_in[5];
    const float* Wv   = (const float*)d_in[6];
    const float* Wo   = (const float*)d_in[7];
    float* Y          = (float*)d_out;

    bf16* Xb  = (bf16*)d_ws;                       // 8388608
    bf16* Wqb = Xb  + (size_t)8388608;             // 4194304
    bf16* Wkb = Wqb + (size_t)4194304;             // 1048576
    bf16* Wvb = Wkb + (size_t)1048576;             // 1048576
    bf16* Wob = Wvb + (size_t)1048576;             // 4194304
    bf16* Qb  = Wob + (size_t)4194304;             // 8388608
    bf16* Kb  = Qb  + (size_t)8388608;             // 2097152
    bf16* Vtb = Kb  + (size_t)2097152;             // 2097152 (transposed d,s)
    bf16* Ob  = Vtb + (size_t)2097152;             // 8388608

    dim3 blk(256);
    cvt_all_kernel<<<dim3(9216), blk, 0, stream>>>(X, Wq, Wk, Wv, Wo,
                                                   Xb, Wqb, Wkb, Wvb, Wob);
    gemm_qkv_kernel<<<dim3(32, 24), blk, 0, stream>>>(Xb, Wqb, Wkb, Wvb,
                                                      cs, sn, Qb, Kb, Vtb);
    attn_kernel<<<dim3(16, H_, B_), blk, 0, stream>>>(Qb, Kb, Vtb, Ob);
    gemm_out_kernel<<<dim3(32, 16), blk, 0, stream>>>(Ob, Wob, Y);
}

// Round 4
// 354.133 us; speedup vs baseline: 1.1813x; 1.1058x over previous
//
#include <hip/hip_runtime.h>
#include <hip/hip_bf16.h>
#include <cstdint>
#include <cstddef>

// Problem constants
#define B_    2
#define S_    2048
#define HID_  2048
#define H_    32
#define HKV_  8
#define DH_   64
// SCALE * log2(e): scores scaled into exp2 domain
#define SC2_  0.1803368801111244f

typedef __bf16 bf16;
typedef bf16  bf16x2 __attribute__((ext_vector_type(2)));
typedef bf16  bf16x4 __attribute__((ext_vector_type(4)));
typedef bf16  bf16x8 __attribute__((ext_vector_type(8)));
typedef float f32x4  __attribute__((ext_vector_type(4)));
typedef float f32x16 __attribute__((ext_vector_type(16)));
typedef uint32_t u32x2 __attribute__((ext_vector_type(2)));

typedef __attribute__((address_space(3))) uint32_t  lds_u32_t;
typedef __attribute__((address_space(1))) const uint32_t glob_u32_t;

__device__ __forceinline__ void async16(const void* g, void* l) {
    __builtin_amdgcn_global_load_lds((glob_u32_t*)g, (lds_u32_t*)l, 16, 0, 0);
}

__device__ __forceinline__ bf16x8 cvt8(float4 a, float4 b) {
    bf16x8 r;
    r[0] = (bf16)a.x; r[1] = (bf16)a.y; r[2] = (bf16)a.z; r[3] = (bf16)a.w;
    r[4] = (bf16)b.x; r[5] = (bf16)b.y; r[6] = (bf16)b.z; r[7] = (bf16)b.w;
    return r;
}

__device__ __forceinline__ uint32_t pkbf(float a, float b) {
    bf16x2 t; t[0] = (bf16)a; t[1] = (bf16)b;
    return __builtin_bit_cast(uint32_t, t);
}
__device__ __forceinline__ bf16x8 mk8(uint32_t a, uint32_t b, uint32_t c, uint32_t d) {
    union { uint32_t u[4]; bf16x8 v; } t;
    t.u[0] = a; t.u[1] = b; t.u[2] = c; t.u[3] = d;
    return t.v;
}

// ---------------------------------------------------------------------------
// Merged fp32->bf16 convert for all 5 tensors (one launch).
// ---------------------------------------------------------------------------
__global__ __launch_bounds__(256) void cvt_all_kernel(
    const float* __restrict__ X,  const float* __restrict__ Wq,
    const float* __restrict__ Wk, const float* __restrict__ Wv,
    const float* __restrict__ Wo,
    bf16* __restrict__ Xb,  bf16* __restrict__ Wqb, bf16* __restrict__ Wkb,
    bf16* __restrict__ Wvb, bf16* __restrict__ Wob)
{
    const int i = blockIdx.x * 256 + threadIdx.x;
    const float* src; bf16* dst; int off;
    if (i < 1048576)      { src = X;  dst = Xb;  off = i; }
    else if (i < 1572864) { src = Wq; dst = Wqb; off = i - 1048576; }
    else if (i < 1703936) { src = Wk; dst = Wkb; off = i - 1572864; }
    else if (i < 1835008) { src = Wv; dst = Wvb; off = i - 1703936; }
    else                  { src = Wo; dst = Wob; off = i - 1835008; }
    float4 a = ((const float4*)src)[2 * off];
    float4 b = ((const float4*)src)[2 * off + 1];
    ((bf16x8*)dst)[off] = cvt8(a, b);
}

// ---------------------------------------------------------------------------
// Fused QKV projection GEMM (m97 structure). V written TRANSPOSED (b,hkv,d,s).
// Q is pre-scaled by SCALE*log2e so attn scores land in exp2 domain directly.
// ---------------------------------------------------------------------------
__global__ __launch_bounds__(256) void gemm_qkv_kernel(
    const bf16* __restrict__ A,
    const bf16* __restrict__ Wqb, const bf16* __restrict__ Wkb,
    const bf16* __restrict__ Wvb,
    const float* __restrict__ cs, const float* __restrict__ sn,
    bf16* __restrict__ Qo, bf16* __restrict__ Ko, bf16* __restrict__ Vt)
{
    __shared__ bf16 a_lds[128 * 64];
    __shared__ bf16 b_lds[128 * 64];

    const int tid  = threadIdx.x;
    const int wave = tid >> 6;
    const int lane = tid & 63;
    const int quad = lane >> 4;
    const int l16  = lane & 15;
    const int wm   = wave >> 1;
    const int wn   = wave & 1;
    const int m0   = blockIdx.x * 128;
    const int n0   = blockIdx.y * 128;

    f32x4 acc[4][4];
    #pragma unroll
    for (int mt = 0; mt < 4; ++mt)
        #pragma unroll
        for (int nt = 0; nt < 4; ++nt)
            acc[mt][nt] = (f32x4){0.f, 0.f, 0.f, 0.f};

    int srow[4], sgcol[4];
    const bf16* browp[4];
    #pragma unroll
    for (int i = 0; i < 4; ++i) {
        const int e = tid * 8 + i * 2048;
        srow[i] = e >> 6;
        const int chunk = (e >> 3) & 7;
        sgcol[i] = (chunk ^ (srow[i] & 7)) << 3;
        const int n = n0 + srow[i];
        browp[i] = (n < 2048) ? (Wqb + (size_t)n * HID_)
                 : (n < 2560) ? (Wkb + (size_t)(n - 2048) * HID_)
                              : (Wvb + (size_t)(n - 2560) * HID_);
    }

    for (int k0 = 0; k0 < HID_; k0 += 64) {
        #pragma unroll
        for (int i = 0; i < 4; ++i) {
            async16(A + (size_t)(m0 + srow[i]) * HID_ + k0 + sgcol[i],
                    &a_lds[tid * 8 + i * 2048]);
            async16(browp[i] + k0 + sgcol[i],
                    &b_lds[tid * 8 + i * 2048]);
        }
        __syncthreads();
        #pragma unroll
        for (int ks = 0; ks < 2; ++ks) {
            bf16x8 af[4], bfr[4];
            #pragma unroll
            for (int mt = 0; mt < 4; ++mt) {
                const int row = wm * 64 + mt * 16 + l16;
                const int c = (ks * 4 + quad) ^ (row & 7);
                af[mt] = *(const bf16x8*)(&a_lds[row * 64 + c * 8]);
            }
            #pragma unroll
            for (int nt = 0; nt < 4; ++nt) {
                const int row = wn * 64 + nt * 16 + l16;
                const int c = (ks * 4 + quad) ^ (row & 7);
                bfr[nt] = *(const bf16x8*)(&b_lds[row * 64 + c * 8]);
            }
            #pragma unroll
            for (int mt = 0; mt < 4; ++mt)
                #pragma unroll
                for (int nt = 0; nt < 4; ++nt)
                    acc[mt][nt] = __builtin_amdgcn_mfma_f32_16x16x32_bf16(
                        af[mt], bfr[nt], acc[mt][nt], 0, 0, 0);
        }
        __syncthreads();
    }

    const int nw = n0 + wn * 64;
    const int d  = l16;
    #pragma unroll
    for (int mt = 0; mt < 4; ++mt) {
        #pragma unroll
        for (int r = 0; r < 4; ++r) {
            const int m  = m0 + wm * 64 + mt * 16 + quad * 4 + r;
            const int bb = m >> 11;
            const int ss = m & (S_ - 1);
            const float v0 = acc[mt][0][r], v1 = acc[mt][1][r];
            const float v2 = acc[mt][2][r], v3 = acc[mt][3][r];
            if (nw < 2048) {
                const int h = nw >> 6;
                bf16* dp = Qo + ((size_t)(bb * H_ + h) * S_ + ss) * DH_;
                const float* cp = cs + ((size_t)bb * S_ + ss) * DH_;
                const float* sp = sn + ((size_t)bb * S_ + ss) * DH_;
                dp[ 0 + d] = (bf16)((v0 * cp[ 0 + d] - v2 * sp[ 0 + d]) * SC2_);
                dp[16 + d] = (bf16)((v1 * cp[16 + d] - v3 * sp[16 + d]) * SC2_);
                dp[32 + d] = (bf16)((v2 * cp[32 + d] + v0 * sp[32 + d]) * SC2_);
                dp[48 + d] = (bf16)((v3 * cp[48 + d] + v1 * sp[48 + d]) * SC2_);
            } else if (nw < 2560) {
                const int h = (nw - 2048) >> 6;
                bf16* dp = Ko + ((size_t)(bb * HKV_ + h) * S_ + ss) * DH_;
                const float* cp = cs + ((size_t)bb * S_ + ss) * DH_;
                const float* sp = sn + ((size_t)bb * S_ + ss) * DH_;
                dp[ 0 + d] = (bf16)(v0 * cp[ 0 + d] - v2 * sp[ 0 + d]);
                dp[16 + d] = (bf16)(v1 * cp[16 + d] - v3 * sp[16 + d]);
                dp[32 + d] = (bf16)(v2 * cp[32 + d] + v0 * sp[32 + d]);
                dp[48 + d] = (bf16)(v3 * cp[48 + d] + v1 * sp[48 + d]);
            } else {
                const int h = (nw - 2560) >> 6;
                bf16* dp = Vt + ((size_t)(bb * HKV_ + h) * DH_) * S_ + ss;
                dp[(size_t)( 0 + d) * S_] = (bf16)v0;
                dp[(size_t)(16 + d) * S_] = (bf16)v1;
                dp[(size_t)(32 + d) * S_] = (bf16)v2;
                dp[(size_t)(48 + d) * S_] = (bf16)v3;
            }
        }
    }
}

// ---------------------------------------------------------------------------
// Output projection: Y (4096 x 2048 fp32) = Ob (bf16, (b,s,h*d)) * Wob^T.
// ---------------------------------------------------------------------------
__global__ __launch_bounds__(256) void gemm_out_kernel(
    const bf16* __restrict__ A, const bf16* __restrict__ Wb,
    float* __restrict__ Y)
{
    __shared__ bf16 a_lds[128 * 64];
    __shared__ bf16 b_lds[128 * 64];

    const int tid  = threadIdx.x;
    const int wave = tid >> 6;
    const int lane = tid & 63;
    const int quad = lane >> 4;
    const int l16  = lane & 15;
    const int wm   = wave >> 1;
    const int wn   = wave & 1;
    const int m0   = blockIdx.x * 128;
    const int n0   = blockIdx.y * 128;

    f32x4 acc[4][4];
    #pragma unroll
    for (int mt = 0; mt < 4; ++mt)
        #pragma unroll
        for (int nt = 0; nt < 4; ++nt)
            acc[mt][nt] = (f32x4){0.f, 0.f, 0.f, 0.f};

    int srow[4], sgcol[4];
    #pragma unroll
    for (int i = 0; i < 4; ++i) {
        const int e = tid * 8 + i * 2048;
        srow[i] = e >> 6;
        const int chunk = (e >> 3) & 7;
        sgcol[i] = (chunk ^ (srow[i] & 7)) << 3;
    }

    for (int k0 = 0; k0 < HID_; k0 += 64) {
        #pragma unroll
        for (int i = 0; i < 4; ++i) {
            async16(A + (size_t)(m0 + srow[i]) * HID_ + k0 + sgcol[i],
                    &a_lds[tid * 8 + i * 2048]);
            async16(Wb + (size_t)(n0 + srow[i]) * HID_ + k0 + sgcol[i],
                    &b_lds[tid * 8 + i * 2048]);
        }
        __syncthreads();
        #pragma unroll
        for (int ks = 0; ks < 2; ++ks) {
            bf16x8 af[4], bfr[4];
            #pragma unroll
            for (int mt = 0; mt < 4; ++mt) {
                const int row = wm * 64 + mt * 16 + l16;
                const int c = (ks * 4 + quad) ^ (row & 7);
                af[mt] = *(const bf16x8*)(&a_lds[row * 64 + c * 8]);
            }
            #pragma unroll
            for (int nt = 0; nt < 4; ++nt) {
                const int row = wn * 64 + nt * 16 + l16;
                const int c = (ks * 4 + quad) ^ (row & 7);
                bfr[nt] = *(const bf16x8*)(&b_lds[row * 64 + c * 8]);
            }
            #pragma unroll
            for (int mt = 0; mt < 4; ++mt)
                #pragma unroll
                for (int nt = 0; nt < 4; ++nt)
                    acc[mt][nt] = __builtin_amdgcn_mfma_f32_16x16x32_bf16(
                        af[mt], bfr[nt], acc[mt][nt], 0, 0, 0);
        }
        __syncthreads();
    }

    #pragma unroll
    for (int mt = 0; mt < 4; ++mt)
        #pragma unroll
        for (int nt = 0; nt < 4; ++nt)
            #pragma unroll
            for (int r = 0; r < 4; ++r) {
                const int m = m0 + wm * 64 + mt * 16 + quad * 4 + r;
                const int n = n0 + wn * 64 + nt * 16 + l16;
                Y[(size_t)m * HID_ + n] = acc[mt][nt][r];
            }
}

// ---------------------------------------------------------------------------
// Flash attention v8 (causal, GQA), 32x32x16 MFMA.
// QK swapped (A=K, B=Q) -> S^T (col=q=lane&31); PV swapped (A=V^T, B=P^T) ->
// O^T (col=q) => all softmax state same-lane; stats need 1 shfl_xor(32).
// v8 = round-0 shell (KNOWN GOOD schedule: q-tile pair (qt,15-qt) per block,
// uniform 34 iters, 512 blocks, KVBLK=64, 32 KB LDS dbuf, 1 barrier/iter)
// + HW-validated micro-opts from rounds 2-3 (all passed on MI355X):
//  - Q pre-scaled by SCALE*log2e at projection -> no per-score scale pass
//  - causal mask pass only on partial tiles (full tiles: zero overhead)
//  - defer-max (THR=8 in exp2 domain): skip m/O rescale when growth <= 8
//  - P C->B layout via v_permlane32_swap (8/tile) not 16 shfl + 16 select
//  - V^T fragments loaded after softmax (smaller live range)
//  - s_setprio(1) around MFMA clusters (measured +4-7% attn)
// ---------------------------------------------------------------------------
__global__ __launch_bounds__(256) void attn_kernel(
    const bf16* __restrict__ Q, const bf16* __restrict__ K,
    const bf16* __restrict__ Vt, bf16* __restrict__ O)
{
    __shared__ bf16 k_lds[2][64 * 64];
    __shared__ bf16 v_lds[2][64 * 64];

    const int tid  = threadIdx.x;
    const int wave = tid >> 6;
    const int lane = tid & 63;
    const int l32  = lane & 31;
    const int half = lane >> 5;
    const int h  = blockIdx.y;
    const int b  = blockIdx.z;
    const int hkv = h >> 2;

    const bf16* Qg = Q  + (size_t)(b * H_ + h) * S_ * DH_;
    const bf16* Kg = K  + (size_t)(b * HKV_ + hkv) * S_ * DH_;
    const bf16* Vg = Vt + ((size_t)(b * HKV_ + hkv) * DH_) * S_;

    const int srow0  = tid >> 3;
    const int scolsw = ((tid & 7) ^ ((tid >> 3) & 7)) << 3;

    #pragma unroll 1
    for (int ph = 0; ph < 2; ++ph) {
        const int qt  = ph == 0 ? (int)blockIdx.x : (15 - (int)blockIdx.x);
        const int q0  = qt * 128;
        const int qb0 = q0 + wave * 32;
        const int qa  = qb0 + l32;

        // Q fragments, B-layout: n=l32 -> q, k = c*16 + half*8 + j -> dh
        bf16x8 qf[4];
        #pragma unroll
        for (int c = 0; c < 4; ++c)
            qf[c] = *(const bf16x8*)(Qg + (size_t)qa * DH_ + c * 16 + half * 8);

        f32x16 o_acc[2];
        #pragma unroll
        for (int dt = 0; dt < 2; ++dt)
            #pragma unroll
            for (int e = 0; e < 16; ++e) o_acc[dt][e] = 0.f;
        float m_i = -1e30f, l_i = 0.f;

        const int nkt = 2 * qt + 2;

        // prefetch tile 0
        #pragma unroll
        for (int i = 0; i < 2; ++i) {
            const int row = srow0 + i * 32;
            async16(Kg + (size_t)row * DH_ + scolsw, &k_lds[0][tid * 8 + i * 2048]);
            async16(Vg + (size_t)row * S_  + scolsw, &v_lds[0][tid * 8 + i * 2048]);
        }
        __syncthreads();

        for (int kt = 0; kt < nkt; ++kt) {
            if (kt + 1 < nkt) {
                bf16* kb = k_lds[(kt + 1) & 1];
                bf16* vb = v_lds[(kt + 1) & 1];
                #pragma unroll
                for (int i = 0; i < 2; ++i) {
                    const int row = srow0 + i * 32;
                    async16(Kg + (size_t)((kt + 1) * 64 + row) * DH_ + scolsw,
                            kb + tid * 8 + i * 2048);
                    async16(Vg + (size_t)row * S_ + (kt + 1) * 64 + scolsw,
                            vb + tid * 8 + i * 2048);
                }
            }

            if (kt * 64 <= qb0 + 31) {
                const bf16* kb = k_lds[kt & 1];
                const bf16* vb = v_lds[kt & 1];
                const bool act1 = (kt * 64 + 32) <= (qb0 + 31);

                // scores tile 0 (kpos kt*64 .. +31); Q pre-scaled -> exp2 dom.
                f32x16 s0, s1;
                {
                    bf16x8 kf[4];
                    #pragma unroll
                    for (int c = 0; c < 4; ++c) {
                        const int col = ((2 * c + half) ^ (l32 & 7)) << 3;
                        kf[c] = *(const bf16x8*)(kb + l32 * 64 + col);
                    }
                    f32x16 a;
                    #pragma unroll
                    for (int e = 0; e < 16; ++e) a[e] = 0.f;
                    __builtin_amdgcn_s_setprio(1);
                    #pragma unroll
                    for (int c = 0; c < 4; ++c)
                        a = __builtin_amdgcn_mfma_f32_32x32x16_bf16(kf[c], qf[c], a, 0, 0, 0);
                    __builtin_amdgcn_s_setprio(0);
                    s0 = a;
                }
                if (act1) {
                    bf16x8 kf[4];
                    #pragma unroll
                    for (int c = 0; c < 4; ++c) {
                        const int row = 32 + l32;
                        const int col = ((2 * c + half) ^ (row & 7)) << 3;
                        kf[c] = *(const bf16x8*)(kb + row * 64 + col);
                    }
                    f32x16 a;
                    #pragma unroll
                    for (int e = 0; e < 16; ++e) a[e] = 0.f;
                    __builtin_amdgcn_s_setprio(1);
                    #pragma unroll
                    for (int c = 0; c < 4; ++c)
                        a = __builtin_amdgcn_mfma_f32_32x32x16_bf16(kf[c], qf[c], a, 0, 0, 0);
                    __builtin_amdgcn_s_setprio(0);
                    s1 = a;
                }

                // causal mask (partial tiles only; full tiles: no pass)
                if (!((kt * 64 + 31) <= qb0)) {
                    const int qrel = qa - kt * 64 - 4 * half;
                    #pragma unroll
                    for (int e = 0; e < 16; ++e)
                        if (((e & 3) + 8 * (e >> 2)) > qrel) s0[e] = -1e30f;
                }
                if (act1 && !((kt * 64 + 63) <= qb0)) {
                    const int qrel = qa - kt * 64 - 32 - 4 * half;
                    #pragma unroll
                    for (int e = 0; e < 16; ++e)
                        if (((e & 3) + 8 * (e >> 2)) > qrel) s1[e] = -1e30f;
                }

                // stats (per-lane q, combine halves with one xor-32)
                float mx = s0[0];
                #pragma unroll
                for (int e = 1; e < 16; ++e) mx = fmaxf(mx, s0[e]);
                if (act1)
                    #pragma unroll
                    for (int e = 0; e < 16; ++e) mx = fmaxf(mx, s1[e]);
                mx = fmaxf(mx, __shfl_xor(mx, 32));

                // defer-max: only rescale when tile max grew past m_i + 8
                float al = 1.f;
                if (!__all(mx <= m_i + 8.f)) {
                    const float mn = fmaxf(m_i, mx);
                    al = exp2f(m_i - mn);
                    m_i = mn;
                    #pragma unroll
                    for (int dt = 0; dt < 2; ++dt)
                        #pragma unroll
                        for (int e = 0; e < 16; ++e) o_acc[dt][e] *= al;
                }

                float sm = 0.f;
                #pragma unroll
                for (int e = 0; e < 16; ++e) {
                    const float pp = exp2f(s0[e] - m_i);
                    s0[e] = pp; sm += pp;
                }
                if (act1)
                    #pragma unroll
                    for (int e = 0; e < 16; ++e) {
                        const float pp = exp2f(s1[e] - m_i);
                        s1[e] = pp; sm += pp;
                    }
                sm += __shfl_xor(sm, 32);
                l_i = l_i * al + sm;

                // P: C-layout -> B-layout via v_permlane32_swap.
                bf16x8 pf[4];
                {
                    uint32_t d0 = pkbf(s0[0],  s0[1]),  d1 = pkbf(s0[2],  s0[3]);
                    uint32_t d2 = pkbf(s0[4],  s0[5]),  d3 = pkbf(s0[6],  s0[7]);
                    uint32_t d4 = pkbf(s0[8],  s0[9]),  d5 = pkbf(s0[10], s0[11]);
                    uint32_t d6 = pkbf(s0[12], s0[13]), d7 = pkbf(s0[14], s0[15]);
                    u32x2 r02 = __builtin_amdgcn_permlane32_swap(d0, d2, false, false);
                    u32x2 r13 = __builtin_amdgcn_permlane32_swap(d1, d3, false, false);
                    u32x2 r46 = __builtin_amdgcn_permlane32_swap(d4, d6, false, false);
                    u32x2 r57 = __builtin_amdgcn_permlane32_swap(d5, d7, false, false);
                    pf[0] = mk8(r02[0], r13[0], r02[1], r13[1]);
                    pf[1] = mk8(r46[0], r57[0], r46[1], r57[1]);
                }
                if (act1) {
                    uint32_t d0 = pkbf(s1[0],  s1[1]),  d1 = pkbf(s1[2],  s1[3]);
                    uint32_t d2 = pkbf(s1[4],  s1[5]),  d3 = pkbf(s1[6],  s1[7]);
                    uint32_t d4 = pkbf(s1[8],  s1[9]),  d5 = pkbf(s1[10], s1[11]);
                    uint32_t d6 = pkbf(s1[12], s1[13]), d7 = pkbf(s1[14], s1[15]);
                    u32x2 r02 = __builtin_amdgcn_permlane32_swap(d0, d2, false, false);
                    u32x2 r13 = __builtin_amdgcn_permlane32_swap(d1, d3, false, false);
                    u32x2 r46 = __builtin_amdgcn_permlane32_swap(d4, d6, false, false);
                    u32x2 r57 = __builtin_amdgcn_permlane32_swap(d5, d7, false, false);
                    pf[2] = mk8(r02[0], r13[0], r02[1], r13[1]);
                    pf[3] = mk8(r46[0], r57[0], r46[1], r57[1]);
                }

                // V^T A-frags (loaded late, only needed for PV):
                // vf[dt][c] = V^T[dt*32+l32][c*16+half*8 ..+8]
                bf16x8 vf[2][4];
                #pragma unroll
                for (int dt = 0; dt < 2; ++dt)
                    #pragma unroll
                    for (int c = 0; c < 4; ++c) {
                        const int row = dt * 32 + l32;
                        const int col = ((2 * c + half) ^ (row & 7)) << 3;
                        vf[dt][c] = *(const bf16x8*)(vb + row * 64 + col);
                    }

                // O^T += V^T * P^T over kpos chunks
                const int nc = act1 ? 4 : 2;
                __builtin_amdgcn_s_setprio(1);
                #pragma unroll
                for (int c = 0; c < 4; ++c) {
                    if (c >= nc) break;
                    #pragma unroll
                    for (int dt = 0; dt < 2; ++dt)
                        o_acc[dt] = __builtin_amdgcn_mfma_f32_32x32x16_bf16(
                            vf[dt][c], pf[c], o_acc[dt], 0, 0, 0);
                }
                __builtin_amdgcn_s_setprio(0);
            }
            __syncthreads();
        }

        // epilogue: O^T C-layout -> Ob (b, s, h*64+d); q = l32 same-lane
        const float inv = 1.f / l_i;
        bf16* op = O + ((size_t)(b * S_ + qa) * H_ + h) * DH_;
        #pragma unroll
        for (int dt = 0; dt < 2; ++dt)
            #pragma unroll
            for (int g = 0; g < 4; ++g) {
                bf16x4 ov;
                #pragma unroll
                for (int r = 0; r < 4; ++r) ov[r] = (bf16)(o_acc[dt][g * 4 + r] * inv);
                *(bf16x4*)(op + dt * 32 + g * 8 + half * 4) = ov;
            }
        __syncthreads();   // LDS reuse safety before next phase's prefetch
    }
}

// ---------------------------------------------------------------------------
extern "C" void kernel_launch(void* const* d_in, const int* in_sizes, int n_in,
                              void* d_out, int out_size, void* d_ws, size_t ws_size,
                              hipStream_t stream)
{
    const float* X    = (const float*)d_in[0];
    const float* cs   = (const float*)d_in[1];
    const float* sn   = (const float*)d_in[2];
    const float* Wq   = (const float*)d_in[4];
    const float* Wk   = (const float*)d_in[5];
    const float* Wv   = (const float*)d_in[6];
    const float* Wo   = (const float*)d_in[7];
    float* Y          = (float*)d_out;

    bf16* Xb  = (bf16*)d_ws;                       // 8388608
    bf16* Wqb = Xb  + (size_t)8388608;             // 4194304
    bf16* Wkb = Wqb + (size_t)4194304;             // 1048576
    bf16* Wvb = Wkb + (size_t)1048576;             // 1048576
    bf16* Wob = Wvb + (size_t)1048576;             // 4194304
    bf16* Qb  = Wob + (size_t)4194304;             // 8388608
    bf16* Kb  = Qb  + (size_t)8388608;             // 2097152
    bf16* Vtb = Kb  + (size_t)2097152;             // 2097152 (transposed d,s)
    bf16* Ob  = Vtb + (size_t)2097152;             // 8388608

    dim3 blk(256);
    cvt_all_kernel<<<dim3(9216), blk, 0, stream>>>(X, Wq, Wk, Wv, Wo,
                                                   Xb, Wqb, Wkb, Wvb, Wob);
    gemm_qkv_kernel<<<dim3(32, 24), blk, 0, stream>>>(Xb, Wqb, Wkb, Wvb,
                                                      cs, sn, Qb, Kb, Vtb);
    attn_kernel<<<dim3(8, H_, B_), blk, 0, stream>>>(Qb, Kb, Vtb, Ob);
    gemm_out_kernel<<<dim3(32, 16), blk, 0, stream>>>(Ob, Wob, Y);
}

// Round 5
// 349.019 us; speedup vs baseline: 1.1986x; 1.0147x over previous
//
#include <hip/hip_runtime.h>
#include <hip/hip_bf16.h>
#include <cstdint>
#include <cstddef>

// Problem constants
#define B_    2
#define S_    2048
#define HID_  2048
#define H_    32
#define HKV_  8
#define DH_   64
// SCALE * log2(e): scores scaled into exp2 domain
#define SC2_  0.1803368801111244f

typedef __bf16 bf16;
typedef bf16  bf16x2 __attribute__((ext_vector_type(2)));
typedef bf16  bf16x4 __attribute__((ext_vector_type(4)));
typedef bf16  bf16x8 __attribute__((ext_vector_type(8)));
typedef float f32x4  __attribute__((ext_vector_type(4)));
typedef float f32x16 __attribute__((ext_vector_type(16)));
typedef uint32_t u32x2 __attribute__((ext_vector_type(2)));

typedef __attribute__((address_space(3))) uint32_t  lds_u32_t;
typedef __attribute__((address_space(1))) const uint32_t glob_u32_t;

__device__ __forceinline__ void async16(const void* g, void* l) {
    __builtin_amdgcn_global_load_lds((glob_u32_t*)g, (lds_u32_t*)l, 16, 0, 0);
}

__device__ __forceinline__ bf16x8 cvt8(float4 a, float4 b) {
    bf16x8 r;
    r[0] = (bf16)a.x; r[1] = (bf16)a.y; r[2] = (bf16)a.z; r[3] = (bf16)a.w;
    r[4] = (bf16)b.x; r[5] = (bf16)b.y; r[6] = (bf16)b.z; r[7] = (bf16)b.w;
    return r;
}

__device__ __forceinline__ uint32_t pkbf(float a, float b) {
    bf16x2 t; t[0] = (bf16)a; t[1] = (bf16)b;
    return __builtin_bit_cast(uint32_t, t);
}
__device__ __forceinline__ bf16x8 mk8(uint32_t a, uint32_t b, uint32_t c, uint32_t d) {
    union { uint32_t u[4]; bf16x8 v; } t;
    t.u[0] = a; t.u[1] = b; t.u[2] = c; t.u[3] = d;
    return t.v;
}

// ---------------------------------------------------------------------------
// Merged fp32->bf16 convert for all 5 tensors (one launch).
// ---------------------------------------------------------------------------
__global__ __launch_bounds__(256) void cvt_all_kernel(
    const float* __restrict__ X,  const float* __restrict__ Wq,
    const float* __restrict__ Wk, const float* __restrict__ Wv,
    const float* __restrict__ Wo,
    bf16* __restrict__ Xb,  bf16* __restrict__ Wqb, bf16* __restrict__ Wkb,
    bf16* __restrict__ Wvb, bf16* __restrict__ Wob)
{
    const int i = blockIdx.x * 256 + threadIdx.x;
    const float* src; bf16* dst; int off;
    if (i < 1048576)      { src = X;  dst = Xb;  off = i; }
    else if (i < 1572864) { src = Wq; dst = Wqb; off = i - 1048576; }
    else if (i < 1703936) { src = Wk; dst = Wkb; off = i - 1572864; }
    else if (i < 1835008) { src = Wv; dst = Wvb; off = i - 1703936; }
    else                  { src = Wo; dst = Wob; off = i - 1835008; }
    float4 a = ((const float4*)src)[2 * off];
    float4 b = ((const float4*)src)[2 * off + 1];
    ((bf16x8*)dst)[off] = cvt8(a, b);
}

// ---------------------------------------------------------------------------
// Fused QKV projection GEMM. V written TRANSPOSED (b,hkv,d,s).
// Q pre-scaled by SCALE*log2e so attn scores land in exp2 domain directly.
// v2 (round 5): T3 minimum 2-phase pipeline — double-buffered LDS, STAGE(t+1)
// issued BEFORE compute(t), ONE barrier per K-step (its implicit vmcnt(0)
// drain lands after the MFMAs, hiding HBM->LDS latency under compute).
// + T1 bijective XCD swizzle (768 blocks, 96/XCD chunks).
// ---------------------------------------------------------------------------
__global__ __launch_bounds__(256) void gemm_qkv_kernel(
    const bf16* __restrict__ A,
    const bf16* __restrict__ Wqb, const bf16* __restrict__ Wkb,
    const bf16* __restrict__ Wvb,
    const float* __restrict__ cs, const float* __restrict__ sn,
    bf16* __restrict__ Qo, bf16* __restrict__ Ko, bf16* __restrict__ Vt)
{
    __shared__ bf16 a_lds[2][128 * 64];
    __shared__ bf16 b_lds[2][128 * 64];

    const int tid  = threadIdx.x;
    const int wave = tid >> 6;
    const int lane = tid & 63;
    const int quad = lane >> 4;
    const int l16  = lane & 15;
    const int wm   = wave >> 1;
    const int wn   = wave & 1;

    // XCD-aware swizzle: 768 blocks -> 8 chunks of 96 contiguous tiles
    const int idx = blockIdx.x + 32 * blockIdx.y;
    const int swz = (idx & 7) * 96 + (idx >> 3);
    const int m0  = (swz & 31) * 128;
    const int n0  = (swz >> 5) * 128;

    f32x4 acc[4][4];
    #pragma unroll
    for (int mt = 0; mt < 4; ++mt)
        #pragma unroll
        for (int nt = 0; nt < 4; ++nt)
            acc[mt][nt] = (f32x4){0.f, 0.f, 0.f, 0.f};

    int srow[4], sgcol[4];
    const bf16* browp[4];
    #pragma unroll
    for (int i = 0; i < 4; ++i) {
        const int e = tid * 8 + i * 2048;
        srow[i] = e >> 6;
        const int chunk = (e >> 3) & 7;
        sgcol[i] = (chunk ^ (srow[i] & 7)) << 3;
        const int n = n0 + srow[i];
        browp[i] = (n < 2048) ? (Wqb + (size_t)n * HID_)
                 : (n < 2560) ? (Wkb + (size_t)(n - 2048) * HID_)
                              : (Wvb + (size_t)(n - 2560) * HID_);
    }

    // prologue: stage K-tile 0 into buffer 0
    #pragma unroll
    for (int i = 0; i < 4; ++i) {
        async16(A + (size_t)(m0 + srow[i]) * HID_ + sgcol[i],
                &a_lds[0][tid * 8 + i * 2048]);
        async16(browp[i] + sgcol[i],
                &b_lds[0][tid * 8 + i * 2048]);
    }
    __syncthreads();

    for (int k0 = 0; k0 < HID_; k0 += 64) {
        const int cur = (k0 >> 6) & 1;
        if (k0 + 64 < HID_) {
            #pragma unroll
            for (int i = 0; i < 4; ++i) {
                async16(A + (size_t)(m0 + srow[i]) * HID_ + k0 + 64 + sgcol[i],
                        &a_lds[cur ^ 1][tid * 8 + i * 2048]);
                async16(browp[i] + k0 + 64 + sgcol[i],
                        &b_lds[cur ^ 1][tid * 8 + i * 2048]);
            }
        }
        const bf16* al = a_lds[cur];
        const bf16* bl = b_lds[cur];
        #pragma unroll
        for (int ks = 0; ks < 2; ++ks) {
            bf16x8 af[4], bfr[4];
            #pragma unroll
            for (int mt = 0; mt < 4; ++mt) {
                const int row = wm * 64 + mt * 16 + l16;
                const int c = (ks * 4 + quad) ^ (row & 7);
                af[mt] = *(const bf16x8*)(&al[row * 64 + c * 8]);
            }
            #pragma unroll
            for (int nt = 0; nt < 4; ++nt) {
                const int row = wn * 64 + nt * 16 + l16;
                const int c = (ks * 4 + quad) ^ (row & 7);
                bfr[nt] = *(const bf16x8*)(&bl[row * 64 + c * 8]);
            }
            #pragma unroll
            for (int mt = 0; mt < 4; ++mt)
                #pragma unroll
                for (int nt = 0; nt < 4; ++nt)
                    acc[mt][nt] = __builtin_amdgcn_mfma_f32_16x16x32_bf16(
                        af[mt], bfr[nt], acc[mt][nt], 0, 0, 0);
        }
        __syncthreads();   // drains vmcnt(0) (next tile staged) + barrier
    }

    const int nw = n0 + wn * 64;
    const int d  = l16;
    #pragma unroll
    for (int mt = 0; mt < 4; ++mt) {
        #pragma unroll
        for (int r = 0; r < 4; ++r) {
            const int m  = m0 + wm * 64 + mt * 16 + quad * 4 + r;
            const int bb = m >> 11;
            const int ss = m & (S_ - 1);
            const float v0 = acc[mt][0][r], v1 = acc[mt][1][r];
            const float v2 = acc[mt][2][r], v3 = acc[mt][3][r];
            if (nw < 2048) {
                const int h = nw >> 6;
                bf16* dp = Qo + ((size_t)(bb * H_ + h) * S_ + ss) * DH_;
                const float* cp = cs + ((size_t)bb * S_ + ss) * DH_;
                const float* sp = sn + ((size_t)bb * S_ + ss) * DH_;
                dp[ 0 + d] = (bf16)((v0 * cp[ 0 + d] - v2 * sp[ 0 + d]) * SC2_);
                dp[16 + d] = (bf16)((v1 * cp[16 + d] - v3 * sp[16 + d]) * SC2_);
                dp[32 + d] = (bf16)((v2 * cp[32 + d] + v0 * sp[32 + d]) * SC2_);
                dp[48 + d] = (bf16)((v3 * cp[48 + d] + v1 * sp[48 + d]) * SC2_);
            } else if (nw < 2560) {
                const int h = (nw - 2048) >> 6;
                bf16* dp = Ko + ((size_t)(bb * HKV_ + h) * S_ + ss) * DH_;
                const float* cp = cs + ((size_t)bb * S_ + ss) * DH_;
                const float* sp = sn + ((size_t)bb * S_ + ss) * DH_;
                dp[ 0 + d] = (bf16)(v0 * cp[ 0 + d] - v2 * sp[ 0 + d]);
                dp[16 + d] = (bf16)(v1 * cp[16 + d] - v3 * sp[16 + d]);
                dp[32 + d] = (bf16)(v2 * cp[32 + d] + v0 * sp[32 + d]);
                dp[48 + d] = (bf16)(v3 * cp[48 + d] + v1 * sp[48 + d]);
            } else {
                const int h = (nw - 2560) >> 6;
                bf16* dp = Vt + ((size_t)(bb * HKV_ + h) * DH_) * S_ + ss;
                dp[(size_t)( 0 + d) * S_] = (bf16)v0;
                dp[(size_t)(16 + d) * S_] = (bf16)v1;
                dp[(size_t)(32 + d) * S_] = (bf16)v2;
                dp[(size_t)(48 + d) * S_] = (bf16)v3;
            }
        }
    }
}

// ---------------------------------------------------------------------------
// Output projection: Y (4096 x 2048 fp32) = Ob (bf16, (b,s,h*d)) * Wob^T.
// v2 (round 5): same 2-phase pipeline + XCD swizzle (512 blocks, 64/XCD).
// ---------------------------------------------------------------------------
__global__ __launch_bounds__(256) void gemm_out_kernel(
    const bf16* __restrict__ A, const bf16* __restrict__ Wb,
    float* __restrict__ Y)
{
    __shared__ bf16 a_lds[2][128 * 64];
    __shared__ bf16 b_lds[2][128 * 64];

    const int tid  = threadIdx.x;
    const int wave = tid >> 6;
    const int lane = tid & 63;
    const int quad = lane >> 4;
    const int l16  = lane & 15;
    const int wm   = wave >> 1;
    const int wn   = wave & 1;

    const int idx = blockIdx.x + 32 * blockIdx.y;
    const int swz = (idx & 7) * 64 + (idx >> 3);
    const int m0  = (swz & 31) * 128;
    const int n0  = (swz >> 5) * 128;

    f32x4 acc[4][4];
    #pragma unroll
    for (int mt = 0; mt < 4; ++mt)
        #pragma unroll
        for (int nt = 0; nt < 4; ++nt)
            acc[mt][nt] = (f32x4){0.f, 0.f, 0.f, 0.f};

    int srow[4], sgcol[4];
    #pragma unroll
    for (int i = 0; i < 4; ++i) {
        const int e = tid * 8 + i * 2048;
        srow[i] = e >> 6;
        const int chunk = (e >> 3) & 7;
        sgcol[i] = (chunk ^ (srow[i] & 7)) << 3;
    }

    // prologue: stage K-tile 0 into buffer 0
    #pragma unroll
    for (int i = 0; i < 4; ++i) {
        async16(A + (size_t)(m0 + srow[i]) * HID_ + sgcol[i],
                &a_lds[0][tid * 8 + i * 2048]);
        async16(Wb + (size_t)(n0 + srow[i]) * HID_ + sgcol[i],
                &b_lds[0][tid * 8 + i * 2048]);
    }
    __syncthreads();

    for (int k0 = 0; k0 < HID_; k0 += 64) {
        const int cur = (k0 >> 6) & 1;
        if (k0 + 64 < HID_) {
            #pragma unroll
            for (int i = 0; i < 4; ++i) {
                async16(A + (size_t)(m0 + srow[i]) * HID_ + k0 + 64 + sgcol[i],
                        &a_lds[cur ^ 1][tid * 8 + i * 2048]);
                async16(Wb + (size_t)(n0 + srow[i]) * HID_ + k0 + 64 + sgcol[i],
                        &b_lds[cur ^ 1][tid * 8 + i * 2048]);
            }
        }
        const bf16* al = a_lds[cur];
        const bf16* bl = b_lds[cur];
        #pragma unroll
        for (int ks = 0; ks < 2; ++ks) {
            bf16x8 af[4], bfr[4];
            #pragma unroll
            for (int mt = 0; mt < 4; ++mt) {
                const int row = wm * 64 + mt * 16 + l16;
                const int c = (ks * 4 + quad) ^ (row & 7);
                af[mt] = *(const bf16x8*)(&al[row * 64 + c * 8]);
            }
            #pragma unroll
            for (int nt = 0; nt < 4; ++nt) {
                const int row = wn * 64 + nt * 16 + l16;
                const int c = (ks * 4 + quad) ^ (row & 7);
                bfr[nt] = *(const bf16x8*)(&bl[row * 64 + c * 8]);
            }
            #pragma unroll
            for (int mt = 0; mt < 4; ++mt)
                #pragma unroll
                for (int nt = 0; nt < 4; ++nt)
                    acc[mt][nt] = __builtin_amdgcn_mfma_f32_16x16x32_bf16(
                        af[mt], bfr[nt], acc[mt][nt], 0, 0, 0);
        }
        __syncthreads();
    }

    #pragma unroll
    for (int mt = 0; mt < 4; ++mt)
        #pragma unroll
        for (int nt = 0; nt < 4; ++nt)
            #pragma unroll
            for (int r = 0; r < 4; ++r) {
                const int m = m0 + wm * 64 + mt * 16 + quad * 4 + r;
                const int n = n0 + wn * 64 + nt * 16 + l16;
                Y[(size_t)m * HID_ + n] = acc[mt][nt][r];
            }
}

// ---------------------------------------------------------------------------
// Flash attention v8 (causal, GQA), 32x32x16 MFMA — unchanged from round 4.
// QK swapped (A=K, B=Q) -> S^T (col=q=lane&31); PV swapped (A=V^T, B=P^T) ->
// O^T (col=q) => all softmax state same-lane; stats need 1 shfl_xor(32).
// Round-0 shell (q-tile pair (qt,15-qt), uniform 34 iters, 512 blocks,
// KVBLK=64, 32 KB LDS dbuf, 1 barrier/iter) + validated micro-opts:
// Q pre-scaled, partial-tile-only masking, defer-max, permlane32_swap
// P-transpose, late V-frag load, setprio around MFMA.
// ---------------------------------------------------------------------------
__global__ __launch_bounds__(256) void attn_kernel(
    const bf16* __restrict__ Q, const bf16* __restrict__ K,
    const bf16* __restrict__ Vt, bf16* __restrict__ O)
{
    __shared__ bf16 k_lds[2][64 * 64];
    __shared__ bf16 v_lds[2][64 * 64];

    const int tid  = threadIdx.x;
    const int wave = tid >> 6;
    const int lane = tid & 63;
    const int l32  = lane & 31;
    const int half = lane >> 5;
    const int h  = blockIdx.y;
    const int b  = blockIdx.z;
    const int hkv = h >> 2;

    const bf16* Qg = Q  + (size_t)(b * H_ + h) * S_ * DH_;
    const bf16* Kg = K  + (size_t)(b * HKV_ + hkv) * S_ * DH_;
    const bf16* Vg = Vt + ((size_t)(b * HKV_ + hkv) * DH_) * S_;

    const int srow0  = tid >> 3;
    const int scolsw = ((tid & 7) ^ ((tid >> 3) & 7)) << 3;

    #pragma unroll 1
    for (int ph = 0; ph < 2; ++ph) {
        const int qt  = ph == 0 ? (int)blockIdx.x : (15 - (int)blockIdx.x);
        const int q0  = qt * 128;
        const int qb0 = q0 + wave * 32;
        const int qa  = qb0 + l32;

        // Q fragments, B-layout: n=l32 -> q, k = c*16 + half*8 + j -> dh
        bf16x8 qf[4];
        #pragma unroll
        for (int c = 0; c < 4; ++c)
            qf[c] = *(const bf16x8*)(Qg + (size_t)qa * DH_ + c * 16 + half * 8);

        f32x16 o_acc[2];
        #pragma unroll
        for (int dt = 0; dt < 2; ++dt)
            #pragma unroll
            for (int e = 0; e < 16; ++e) o_acc[dt][e] = 0.f;
        float m_i = -1e30f, l_i = 0.f;

        const int nkt = 2 * qt + 2;

        // prefetch tile 0
        #pragma unroll
        for (int i = 0; i < 2; ++i) {
            const int row = srow0 + i * 32;
            async16(Kg + (size_t)row * DH_ + scolsw, &k_lds[0][tid * 8 + i * 2048]);
            async16(Vg + (size_t)row * S_  + scolsw, &v_lds[0][tid * 8 + i * 2048]);
        }
        __syncthreads();

        for (int kt = 0; kt < nkt; ++kt) {
            if (kt + 1 < nkt) {
                bf16* kb = k_lds[(kt + 1) & 1];
                bf16* vb = v_lds[(kt + 1) & 1];
                #pragma unroll
                for (int i = 0; i < 2; ++i) {
                    const int row = srow0 + i * 32;
                    async16(Kg + (size_t)((kt + 1) * 64 + row) * DH_ + scolsw,
                            kb + tid * 8 + i * 2048);
                    async16(Vg + (size_t)row * S_ + (kt + 1) * 64 + scolsw,
                            vb + tid * 8 + i * 2048);
                }
            }

            if (kt * 64 <= qb0 + 31) {
                const bf16* kb = k_lds[kt & 1];
                const bf16* vb = v_lds[kt & 1];
                const bool act1 = (kt * 64 + 32) <= (qb0 + 31);

                // scores tile 0 (kpos kt*64 .. +31); Q pre-scaled -> exp2 dom.
                f32x16 s0, s1;
                {
                    bf16x8 kf[4];
                    #pragma unroll
                    for (int c = 0; c < 4; ++c) {
                        const int col = ((2 * c + half) ^ (l32 & 7)) << 3;
                        kf[c] = *(const bf16x8*)(kb + l32 * 64 + col);
                    }
                    f32x16 a;
                    #pragma unroll
                    for (int e = 0; e < 16; ++e) a[e] = 0.f;
                    __builtin_amdgcn_s_setprio(1);
                    #pragma unroll
                    for (int c = 0; c < 4; ++c)
                        a = __builtin_amdgcn_mfma_f32_32x32x16_bf16(kf[c], qf[c], a, 0, 0, 0);
                    __builtin_amdgcn_s_setprio(0);
                    s0 = a;
                }
                if (act1) {
                    bf16x8 kf[4];
                    #pragma unroll
                    for (int c = 0; c < 4; ++c) {
                        const int row = 32 + l32;
                        const int col = ((2 * c + half) ^ (row & 7)) << 3;
                        kf[c] = *(const bf16x8*)(kb + row * 64 + col);
                    }
                    f32x16 a;
                    #pragma unroll
                    for (int e = 0; e < 16; ++e) a[e] = 0.f;
                    __builtin_amdgcn_s_setprio(1);
                    #pragma unroll
                    for (int c = 0; c < 4; ++c)
                        a = __builtin_amdgcn_mfma_f32_32x32x16_bf16(kf[c], qf[c], a, 0, 0, 0);
                    __builtin_amdgcn_s_setprio(0);
                    s1 = a;
                }

                // causal mask (partial tiles only; full tiles: no pass)
                if (!((kt * 64 + 31) <= qb0)) {
                    const int qrel = qa - kt * 64 - 4 * half;
                    #pragma unroll
                    for (int e = 0; e < 16; ++e)
                        if (((e & 3) + 8 * (e >> 2)) > qrel) s0[e] = -1e30f;
                }
                if (act1 && !((kt * 64 + 63) <= qb0)) {
                    const int qrel = qa - kt * 64 - 32 - 4 * half;
                    #pragma unroll
                    for (int e = 0; e < 16; ++e)
                        if (((e & 3) + 8 * (e >> 2)) > qrel) s1[e] = -1e30f;
                }

                // stats (per-lane q, combine halves with one xor-32)
                float mx = s0[0];
                #pragma unroll
                for (int e = 1; e < 16; ++e) mx = fmaxf(mx, s0[e]);
                if (act1)
                    #pragma unroll
                    for (int e = 0; e < 16; ++e) mx = fmaxf(mx, s1[e]);
                mx = fmaxf(mx, __shfl_xor(mx, 32));

                // defer-max: only rescale when tile max grew past m_i + 8
                float al = 1.f;
                if (!__all(mx <= m_i + 8.f)) {
                    const float mn = fmaxf(m_i, mx);
                    al = exp2f(m_i - mn);
                    m_i = mn;
                    #pragma unroll
                    for (int dt = 0; dt < 2; ++dt)
                        #pragma unroll
                        for (int e = 0; e < 16; ++e) o_acc[dt][e] *= al;
                }

                float sm = 0.f;
                #pragma unroll
                for (int e = 0; e < 16; ++e) {
                    const float pp = exp2f(s0[e] - m_i);
                    s0[e] = pp; sm += pp;
                }
                if (act1)
                    #pragma unroll
                    for (int e = 0; e < 16; ++e) {
                        const float pp = exp2f(s1[e] - m_i);
                        s1[e] = pp; sm += pp;
                    }
                sm += __shfl_xor(sm, 32);
                l_i = l_i * al + sm;

                // P: C-layout -> B-layout via v_permlane32_swap.
                bf16x8 pf[4];
                {
                    uint32_t d0 = pkbf(s0[0],  s0[1]),  d1 = pkbf(s0[2],  s0[3]);
                    uint32_t d2 = pkbf(s0[4],  s0[5]),  d3 = pkbf(s0[6],  s0[7]);
                    uint32_t d4 = pkbf(s0[8],  s0[9]),  d5 = pkbf(s0[10], s0[11]);
                    uint32_t d6 = pkbf(s0[12], s0[13]), d7 = pkbf(s0[14], s0[15]);
                    u32x2 r02 = __builtin_amdgcn_permlane32_swap(d0, d2, false, false);
                    u32x2 r13 = __builtin_amdgcn_permlane32_swap(d1, d3, false, false);
                    u32x2 r46 = __builtin_amdgcn_permlane32_swap(d4, d6, false, false);
                    u32x2 r57 = __builtin_amdgcn_permlane32_swap(d5, d7, false, false);
                    pf[0] = mk8(r02[0], r13[0], r02[1], r13[1]);
                    pf[1] = mk8(r46[0], r57[0], r46[1], r57[1]);
                }
                if (act1) {
                    uint32_t d0 = pkbf(s1[0],  s1[1]),  d1 = pkbf(s1[2],  s1[3]);
                    uint32_t d2 = pkbf(s1[4],  s1[5]),  d3 = pkbf(s1[6],  s1[7]);
                    uint32_t d4 = pkbf(s1[8],  s1[9]),  d5 = pkbf(s1[10], s1[11]);
                    uint32_t d6 = pkbf(s1[12], s1[13]), d7 = pkbf(s1[14], s1[15]);
                    u32x2 r02 = __builtin_amdgcn_permlane32_swap(d0, d2, false, false);
                    u32x2 r13 = __builtin_amdgcn_permlane32_swap(d1, d3, false, false);
                    u32x2 r46 = __builtin_amdgcn_permlane32_swap(d4, d6, false, false);
                    u32x2 r57 = __builtin_amdgcn_permlane32_swap(d5, d7, false, false);
                    pf[2] = mk8(r02[0], r13[0], r02[1], r13[1]);
                    pf[3] = mk8(r46[0], r57[0], r46[1], r57[1]);
                }

                // V^T A-frags (loaded late, only needed for PV):
                // vf[dt][c] = V^T[dt*32+l32][c*16+half*8 ..+8]
                bf16x8 vf[2][4];
                #pragma unroll
                for (int dt = 0; dt < 2; ++dt)
                    #pragma unroll
                    for (int c = 0; c < 4; ++c) {
                        const int row = dt * 32 + l32;
                        const int col = ((2 * c + half) ^ (row & 7)) << 3;
                        vf[dt][c] = *(const bf16x8*)(vb + row * 64 + col);
                    }

                // O^T += V^T * P^T over kpos chunks
                const int nc = act1 ? 4 : 2;
                __builtin_amdgcn_s_setprio(1);
                #pragma unroll
                for (int c = 0; c < 4; ++c) {
                    if (c >= nc) break;
                    #pragma unroll
                    for (int dt = 0; dt < 2; ++dt)
                        o_acc[dt] = __builtin_amdgcn_mfma_f32_32x32x16_bf16(
                            vf[dt][c], pf[c], o_acc[dt], 0, 0, 0);
                }
                __builtin_amdgcn_s_setprio(0);
            }
            __syncthreads();
        }

        // epilogue: O^T C-layout -> Ob (b, s, h*64+d); q = l32 same-lane
        const float inv = 1.f / l_i;
        bf16* op = O + ((size_t)(b * S_ + qa) * H_ + h) * DH_;
        #pragma unroll
        for (int dt = 0; dt < 2; ++dt)
            #pragma unroll
            for (int g = 0; g < 4; ++g) {
                bf16x4 ov;
                #pragma unroll
                for (int r = 0; r < 4; ++r) ov[r] = (bf16)(o_acc[dt][g * 4 + r] * inv);
                *(bf16x4*)(op + dt * 32 + g * 8 + half * 4) = ov;
            }
        __syncthreads();   // LDS reuse safety before next phase's prefetch
    }
}

// ---------------------------------------------------------------------------
extern "C" void kernel_launch(void* const* d_in, const int* in_sizes, int n_in,
                              void* d_out, int out_size, void* d_ws, size_t ws_size,
                              hipStream_t stream)
{
    const float* X    = (const float*)d_in[0];
    const float* cs   = (const float*)d_in[1];
    const float* sn   = (const float*)d_in[2];
    const float* Wq   = (const float*)d_in[4];
    const float* Wk   = (const float*)d_in[5];
    const float* Wv   = (const float*)d_in[6];
    const float* Wo   = (const float*)d_in[7];
    float* Y          = (float*)d_out;

    bf16* Xb  = (bf16*)d_ws;                       // 8388608
    bf16* Wqb = Xb  + (size_t)8388608;             // 4194304
    bf16* Wkb = Wqb + (size_t)4194304;             // 1048576
    bf16* Wvb = Wkb + (size_t)1048576;             // 1048576
    bf16* Wob = Wvb + (size_t)1048576;             // 4194304
    bf16* Qb  = Wob + (size_t)4194304;             // 8388608
    bf16* Kb  = Qb  + (size_t)8388608;             // 2097152
    bf16* Vtb = Kb  + (size_t)2097152;             // 2097152 (transposed d,s)
    bf16* Ob  = Vtb + (size_t)2097152;             // 8388608

    dim3 blk(256);
    cvt_all_kernel<<<dim3(9216), blk, 0, stream>>>(X, Wq, Wk, Wv, Wo,
                                                   Xb, Wqb, Wkb, Wvb, Wob);
    gemm_qkv_kernel<<<dim3(32, 24), blk, 0, stream>>>(Xb, Wqb, Wkb, Wvb,
                                                      cs, sn, Qb, Kb, Vtb);
    attn_kernel<<<dim3(8, H_, B_), blk, 0, stream>>>(Qb, Kb, Vtb, Ob);
    gemm_out_kernel<<<dim3(32, 16), blk, 0, stream>>>(Ob, Wob, Y);
}